// Round 18
// baseline (874.590 us; speedup 1.0000x reference)
//
#include <hip/hip_runtime.h>
#include <math.h>

#define N_NODES 100000
#define N_EDGES 1600000
#define N_GRAPHS 64
#define IN_CH 128
#define DIM 64
#define N_CONVS 3
#define NBLK 196      // ceil(100000/512)
#define NPASS 8
#define PASS_SZ 12500  // N_NODES / NPASS

typedef const float* fp;
typedef unsigned int u32;
typedef unsigned short u16;
typedef __attribute__((ext_vector_type(8))) short short8v;
typedef __attribute__((ext_vector_type(4))) float f32x4;

__device__ inline u16 rne_bf16(float f) {
    u32 u = __float_as_uint(f);
    return (u16)((u + 0x7fffu + ((u >> 16) & 1u)) >> 16);
}
__device__ inline float bf16_f(u16 w) { return __uint_as_float((u32)w << 16); }
__device__ inline float bf16lo_f(u32 w) { return __uint_as_float(w << 16); }
__device__ inline float bf16hi_f(u32 w) { return __uint_as_float(w & 0xffff0000u); }
// order-preserving float <-> uint encoding (for atomicMax on floats incl. negatives)
__device__ inline u32 f_enc(float f) {
    u32 u = __float_as_uint(f);
    return (u & 0x80000000u) ? ~u : (u | 0x80000000u);
}
__device__ inline float f_dec(u32 e) {
    u32 u = (e & 0x80000000u) ? (e & 0x7fffffffu) : ~e;
    return __uint_as_float(u);
}

// ---------------- CSR build ----------------
__global__ __launch_bounds__(256) void count_kernel(const int* __restrict__ dst, int* __restrict__ cnt) {
    int j = blockIdx.x * 256 + threadIdx.x;
    if (j < N_EDGES) {
        int d = dst[j];
        if ((unsigned)d < N_NODES) atomicAdd(&cnt[d], 1);
    }
}

__global__ __launch_bounds__(512) void scan1_kernel(const int* __restrict__ cnt, int* __restrict__ rp,
                                                    int* __restrict__ blksum) {
    __shared__ int tmp[512];
    int t = threadIdx.x, i = blockIdx.x * 512 + t;
    int v0 = (i < N_NODES) ? cnt[i] : 0;
    tmp[t] = v0;
    __syncthreads();
    for (int off = 1; off < 512; off <<= 1) {
        int add = (t >= off) ? tmp[t - off] : 0;
        __syncthreads();
        tmp[t] += add;
        __syncthreads();
    }
    if (i < N_NODES) rp[i] = tmp[t] - v0;
    if (t == 511) blksum[blockIdx.x] = tmp[511];
}

__global__ __launch_bounds__(256) void scan2_kernel(int* __restrict__ blksum) {
    __shared__ int tmp[256];
    int t = threadIdx.x;
    int v0 = (t < NBLK) ? blksum[t] : 0;
    tmp[t] = v0;
    __syncthreads();
    for (int off = 1; off < 256; off <<= 1) {
        int add = (t >= off) ? tmp[t - off] : 0;
        __syncthreads();
        tmp[t] += add;
        __syncthreads();
    }
    if (t < NBLK) blksum[t] = tmp[t] - v0;
}

__global__ __launch_bounds__(512) void scan3_kernel(int* __restrict__ rp, const int* __restrict__ blksum,
                                                    int* __restrict__ cursor) {
    int t = threadIdx.x, i = blockIdx.x * 512 + t;
    if (i < N_NODES) {
        int v = rp[i] + blksum[blockIdx.x];
        rp[i] = v;
        cursor[i] = v;
    }
    if (i == 0) rp[N_NODES] = N_EDGES;
}

// range-split scatter with inline ea->bf16 pack: only edges with dst in [lo, hi)
__global__ __launch_bounds__(256) void scatter_pass_kernel(const int* __restrict__ src,
                                                           const int* __restrict__ dst, fp ea,
                                                           int* __restrict__ cursor,
                                                           int* __restrict__ csr_src,
                                                           uint4* __restrict__ eab, int lo, int hi) {
    int j = blockIdx.x * 256 + threadIdx.x;
    if (j < N_EDGES) {
        int d = dst[j];
        if (d < lo || d >= hi || (unsigned)d >= N_NODES) return;
        int pos = atomicAdd(&cursor[d], 1);
        if ((unsigned)pos < N_EDGES) {
            int s = src[j];
            csr_src[pos] = ((unsigned)s < N_NODES) ? s : 0;
            size_t sb = (size_t)j * 7;
            u16 b[8];
#pragma unroll
            for (int c = 0; c < 7; ++c) b[c] = rne_bf16(ea[sb + c]);
            b[7] = 0;
            uint4 o;
            o.x = b[0] | ((u32)b[1] << 16);
            o.y = b[2] | ((u32)b[3] << 16);
            o.z = b[4] | ((u32)b[5] << 16);
            o.w = b[6] | ((u32)b[7] << 16);
            eab[pos] = o;
        }
    }
}

// ---------------- x -> bf16 ----------------
__global__ __launch_bounds__(256) void cvt_bf16_kernel(const float* __restrict__ in, u16* __restrict__ out,
                                                       int n4) {
    int i = blockIdx.x * 256 + threadIdx.x;
    if (i < n4) {
        float4 v = reinterpret_cast<const float4*>(in)[i];
        ushort4 o;
        o.x = rne_bf16(v.x); o.y = rne_bf16(v.y); o.z = rne_bf16(v.z); o.w = rne_bf16(v.w);
        reinterpret_cast<ushort4*>(out)[i] = o;
    }
}

// ---------------- pack W (q|k|v|s -> K x 256) into MFMA B-fragment order ----------------
__global__ __launch_bounds__(256) void packW_kernel(fp Wq, fp Wk, fp Wv, fp Ws, u16* __restrict__ Bp,
                                                    int K) {
    int total = (K / 32) * 16 * 512;
    int tid = blockIdx.x * 256 + threadIdx.x;
    if (tid >= total) return;
    int j = tid & 7, l = (tid >> 3) & 63, fragid = tid >> 9;
    int tk = fragid >> 4, gtn = fragid & 15;
    int k = tk * 32 + ((l >> 4) << 3) + j;
    int n = (gtn << 4) + (l & 15);
    int mat = n >> 6, cn = n & 63;
    fp W = mat == 0 ? Wq : mat == 1 ? Wk : mat == 2 ? Wv : Ws;
    Bp[tid] = rne_bf16(W[k * 64 + cn]);
}

// ---------------- fused MFMA GEMM: q(bf16, *1/8) | kv(dense u32 via LDS pack) | skip(bf16) ----------------
template <int K>
__global__ __launch_bounds__(256) void gemm_mfma_kernel(
    const u16* __restrict__ A, const u16* __restrict__ Bp,
    fp bq, fp bk, fp bv, fp bs,
    u16* __restrict__ qb, u32* __restrict__ kvp, u16* __restrict__ skbb) {
    constexpr int NTK = K / 32;
    __shared__ u16 kls[32][64];
    int wave = threadIdx.x >> 6;  // 0:q 1:k 2:v 3:skip
    int l = threadIdx.x & 63;
    int lr = l & 15, lg = l >> 4;
    int row0 = blockIdx.x * 32;
    short8v a[2][NTK];
#pragma unroll
    for (int mi = 0; mi < 2; ++mi)
#pragma unroll
        for (int tk = 0; tk < NTK; ++tk)
            a[mi][tk] = *reinterpret_cast<const short8v*>(
                &A[(size_t)(row0 + mi * 16 + lr) * K + tk * 32 + lg * 8]);
    f32x4 c[2][4] = {};
#pragma unroll
    for (int tn = 0; tn < 4; ++tn) {
        int gtn = wave * 4 + tn;
#pragma unroll
        for (int tk = 0; tk < NTK; ++tk) {
            short8v b = *reinterpret_cast<const short8v*>(&Bp[((size_t)(tk * 16 + gtn) * 64 + l) * 8]);
            c[0][tn] = __builtin_amdgcn_mfma_f32_16x16x32_bf16(a[0][tk], b, c[0][tn], 0, 0, 0);
            c[1][tn] = __builtin_amdgcn_mfma_f32_16x16x32_bf16(a[1][tk], b, c[1][tn], 0, 0, 0);
        }
    }
    fp bias = wave == 0 ? bq : wave == 1 ? bk : wave == 2 ? bv : bs;
    if (wave == 1) {  // stage k into LDS
#pragma unroll
        for (int tn = 0; tn < 4; ++tn) {
            int cl = tn * 16 + lr;
            float bb = bias[cl];
#pragma unroll
            for (int mi = 0; mi < 2; ++mi)
#pragma unroll
                for (int r = 0; r < 4; ++r) {
                    int rr = mi * 16 + lg * 4 + r;
                    kls[rr][cl] = rne_bf16(c[mi][tn][r] + bb);
                }
        }
    }
    __syncthreads();
    if (wave == 1) return;
#pragma unroll
    for (int tn = 0; tn < 4; ++tn) {
        int cl = tn * 16 + lr;
        float bb = bias[cl];
#pragma unroll
        for (int mi = 0; mi < 2; ++mi)
#pragma unroll
            for (int r = 0; r < 4; ++r) {
                int rr = mi * 16 + lg * 4 + r;
                size_t row = row0 + rr;
                float val = c[mi][tn][r] + bb;
                if (wave == 0) qb[row * 64 + cl] = rne_bf16(val * 0.125f);
                else if (wave == 3) skbb[row * 64 + cl] = rne_bf16(val);
                else kvp[row * 64 + cl] = (u32)kls[rr][cl] | ((u32)rne_bf16(val) << 16);
            }
    }
}

// ---------------- per-node edge aggregation: 1 node per wave, 4 edges in parallel ----------------
__global__ __launch_bounds__(256) void node_kernel(
    const u16* __restrict__ qb, const u32* __restrict__ kvp,
    const u16* __restrict__ skbb, const uint4* __restrict__ eab, fp We,
    const int* __restrict__ row_ptr, const int* __restrict__ csr_src,
    u16* __restrict__ hb, u16* __restrict__ hmaxb, int act, int initmax) {
    int tid = threadIdx.x;
    int lane = tid & 63;
    int g = lane >> 4, fl = lane & 15;
    int n = blockIdx.x * 4 + (tid >> 6);  // one node per wave
    int f0 = fl * 4;
    ushort4 qv = *reinterpret_cast<const ushort4*>(&qb[(size_t)n * 64 + f0]);
    float4 q4;
    q4.x = bf16_f(qv.x); q4.y = bf16_f(qv.y); q4.z = bf16_f(qv.z); q4.w = bf16_f(qv.w);
    // qw_own: lane with fl==c keeps qw[c] = sum_f q[f]*We[c][f] (q prescaled 1/8)
    float qw_own = 0.f;
#pragma unroll
    for (int c = 0; c < 7; ++c) {
        float4 w4 = *reinterpret_cast<const float4*>(&We[c * 64 + f0]);
        float t = q4.x * w4.x + q4.y * w4.y + q4.z * w4.z + q4.w * w4.w;
        t += __shfl_xor(t, 1);
        t += __shfl_xor(t, 2);
        t += __shfl_xor(t, 4);
        t += __shfl_xor(t, 8);
        if (fl == c) qw_own = t;
    }
    int beg = row_ptr[n], end = row_ptr[n + 1];
    float s = 0.f;
    float ax = 0.f, ay = 0.f, az = 0.f, aw = 0.f;
    float r_own = 0.f;  // sum pe * ea[fl] over this group's edges

    for (int p0 = beg; p0 < end; p0 += 64) {
        int navail = end - p0;
        if (navail > 64) navail = 64;
        int sv = csr_src[p0 + (lane < navail ? lane : navail - 1)];  // 64-edge coalesced batch
        for (int t = 0; t < navail; t += 4) {
            int eidx = t + g;               // group's edge within batch
            bool valid = eidx < navail;
            int ec = valid ? eidx : navail - 1;
            int sn = __shfl(sv, ec);
            int pc = p0 + ec;
            uint4 kv4 = *reinterpret_cast<const uint4*>(&kvp[(size_t)sn * 64 + f0]);
            uint4 e4 = eab[pc];
            u32 w01 = (fl & 2) ? e4.y : e4.x;
            u32 w23 = (fl & 2) ? e4.w : e4.z;
            u32 wsel = (fl & 4) ? w23 : w01;
            float e_own = (fl & 1) ? bf16hi_f(wsel) : bf16lo_f(wsel);
            float kf0 = bf16lo_f(kv4.x), vf0 = bf16hi_f(kv4.x);
            float kf1 = bf16lo_f(kv4.y), vf1 = bf16hi_f(kv4.y);
            float kf2 = bf16lo_f(kv4.z), vf2 = bf16hi_f(kv4.z);
            float kf3 = bf16lo_f(kv4.w), vf3 = bf16hi_f(kv4.w);
            float d = q4.x * kf0 + q4.y * kf1 + q4.z * kf2 + q4.w * kf3 + qw_own * e_own;
            d += __shfl_xor(d, 1);
            d += __shfl_xor(d, 2);
            d += __shfl_xor(d, 4);
            d += __shfl_xor(d, 8);
            float pe = valid ? __expf(d) : 0.f;
            s += pe;
            ax += pe * vf0; ay += pe * vf1; az += pe * vf2; aw += pe * vf3;
            r_own += pe * e_own;
        }
    }
    // merge the 4 edge-groups (feature mapping identical across groups)
    s += __shfl_xor(s, 16); s += __shfl_xor(s, 32);
    ax += __shfl_xor(ax, 16); ax += __shfl_xor(ax, 32);
    ay += __shfl_xor(ay, 16); ay += __shfl_xor(ay, 32);
    az += __shfl_xor(az, 16); az += __shfl_xor(az, 32);
    aw += __shfl_xor(aw, 16); aw += __shfl_xor(aw, 32);
    r_own += __shfl_xor(r_own, 16); r_own += __shfl_xor(r_own, 32);

    float inv = 1.f / (s + 1e-16f);
    float o0 = ax, o1 = ay, o2 = az, o3 = aw;
#pragma unroll
    for (int c = 0; c < 7; ++c) {
        float rc = __shfl(r_own, c);  // lane c (group 0) holds channel c total
        o0 += We[c * 64 + f0 + 0] * rc;
        o1 += We[c * 64 + f0 + 1] * rc;
        o2 += We[c * 64 + f0 + 2] * rc;
        o3 += We[c * 64 + f0 + 3] * rc;
    }
    if (g != 0) return;  // one group writes per node
    ushort4 skv = *reinterpret_cast<const ushort4*>(&skbb[(size_t)n * 64 + f0]);
    float4 res;
    res.x = o0 * inv + bf16_f(skv.x);
    res.y = o1 * inv + bf16_f(skv.y);
    res.z = o2 * inv + bf16_f(skv.z);
    res.w = o3 * inv + bf16_f(skv.w);
    if (act) {
        res.x = res.x > 0.f ? res.x : (__expf(res.x) - 1.f);
        res.y = res.y > 0.f ? res.y : (__expf(res.y) - 1.f);
        res.z = res.z > 0.f ? res.z : (__expf(res.z) - 1.f);
        res.w = res.w > 0.f ? res.w : (__expf(res.w) - 1.f);
    }
    ushort4 hb4;
    hb4.x = rne_bf16(res.x); hb4.y = rne_bf16(res.y); hb4.z = rne_bf16(res.z); hb4.w = rne_bf16(res.w);
    *reinterpret_cast<ushort4*>(&hb[(size_t)n * 64 + f0]) = hb4;
    if (initmax) {
        *reinterpret_cast<ushort4*>(&hmaxb[(size_t)n * 64 + f0]) = hb4;
    } else {
        ushort4 hm4 = *reinterpret_cast<const ushort4*>(&hmaxb[(size_t)n * 64 + f0]);
        hm4.x = rne_bf16(fmaxf(bf16_f(hm4.x), res.x));
        hm4.y = rne_bf16(fmaxf(bf16_f(hm4.y), res.y));
        hm4.z = rne_bf16(fmaxf(bf16_f(hm4.z), res.z));
        hm4.w = rne_bf16(fmaxf(bf16_f(hm4.w), res.w));
        *reinterpret_cast<ushort4*>(&hmaxb[(size_t)n * 64 + f0]) = hm4;
    }
}

// ---------------- gate MLP per node (bf16 hmax input, no atomics) ----------------
__global__ __launch_bounds__(256) void gate_kernel(const u16* __restrict__ h, fp g1W, fp g1b, fp g2W,
                                                   fp g2b, float* __restrict__ gate) {
    __shared__ float hs[4][64];
    int w = threadIdx.x >> 6, lane = threadIdx.x & 63;
    int n = blockIdx.x * 4 + w;
    hs[w][lane] = bf16_f(h[(size_t)n * 64 + lane]);
    __syncthreads();
    float a = 0.f;
    for (int f = 0; f < 64; ++f) a += hs[w][f] * g1W[f * 64 + lane];
    a = fmaxf(a + g1b[lane], 0.f);
    float val = a * g2W[lane];
#pragma unroll
    for (int off = 32; off; off >>= 1) val += __shfl_xor(val, off);
    if (lane == 0) gate[n] = val + g2b[0];
}

// per-graph max via wave-segmented atomicMax (~1600 atomics total)
__global__ __launch_bounds__(256) void gmax_kernel(const float* __restrict__ gate,
                                                   const int* __restrict__ batch,
                                                   u32* __restrict__ gmaxEnc) {
    int i = blockIdx.x * 256 + threadIdx.x;
    if (i >= N_NODES) return;
    int lane = threadIdx.x & 63;
    int g = batch[i];
    u32 e = f_enc(gate[i]);
    int waveBase = i - lane;
    if (waveBase + 63 < N_NODES) {
        int g0 = __shfl(g, 0), g63 = __shfl(g, 63);
        if (g0 == g63) {
            u32 t = e;
#pragma unroll
            for (int off = 32; off; off >>= 1) t = max(t, (u32)__shfl_xor((int)t, off));
            if (lane == 0) atomicMax(&gmaxEnc[g], t);
            return;
        }
    }
    atomicMax(&gmaxEnc[g], e);
}

// exp + per-graph sum; overwrites gate[i] with exp(gate-m)
__global__ __launch_bounds__(256) void expsum_kernel(const int* __restrict__ batch,
                                                     const u32* __restrict__ gmaxEnc,
                                                     float* __restrict__ gate, float* __restrict__ gsum) {
    int i = blockIdx.x * 256 + threadIdx.x;
    if (i >= N_NODES) return;
    int lane = threadIdx.x & 63;
    int g = batch[i];
    float p = __expf(gate[i] - f_dec(gmaxEnc[g]));
    gate[i] = p;
    int waveBase = i - lane;
    bool fullWave = (waveBase + 63 < N_NODES);
    if (fullWave) {
        int g0 = __shfl(g, 0), g63 = __shfl(g, 63);
        if (g0 == g63) {
            float t = p;
#pragma unroll
            for (int off = 32; off; off >>= 1) t += __shfl_xor(t, off);
            if (lane == 0) atomicAdd(&gsum[g], t);
            return;
        }
    }
    atomicAdd(&gsum[g], p);
}

// chunked weighted accumulation: pooled[g][f] += gate[i] * h[i][f]  (bf16 h)
#define PCHUNK 256
__global__ __launch_bounds__(256) void pool_accum_kernel(const u16* __restrict__ h,
                                                         const float* __restrict__ gate,
                                                         const int* __restrict__ batch,
                                                         float* __restrict__ pooled) {
    int w = threadIdx.x >> 6, lane = threadIdx.x & 63;
    int base = blockIdx.x * PCHUNK;
    float acc = 0.f;
    int cur = -1;
    for (int t = 0; t < PCHUNK / 4; ++t) {
        int i = base + w + 4 * t;
        if (i >= N_NODES) break;
        int g = batch[i];
        if (g != cur) {
            if (cur >= 0) atomicAdd(&pooled[cur * 64 + lane], acc);
            acc = 0.f;
            cur = g;
        }
        acc += gate[i] * bf16_f(h[(size_t)i * 64 + lane]);
    }
    if (cur >= 0) atomicAdd(&pooled[cur * 64 + lane], acc);
}

// ---------------- 6-expert MLP head (f32 output); divides pooled by gsum ----------------
__global__ __launch_bounds__(256) void mlp_kernel(const float* __restrict__ pooled,
                                                  const float* __restrict__ gsum, fp m0W, fp m0b, fp m1W,
                                                  fp m1b, fp m2W, fp m2b, fp m3W, fp m3b,
                                                  float* __restrict__ out) {
    int e = blockIdx.x, tid = threadIdx.x;
    __shared__ float P[64 * 64];
    __shared__ float A1[64 * 32];
    __shared__ float A2[64 * 16];
    __shared__ float A3[64 * 8];
    for (int i = tid; i < 64 * 64; i += 256) P[i] = pooled[i] / (gsum[i >> 6] + 1e-16f);
    __syncthreads();
    fp W0 = m0W + e * 64 * 32; fp B0 = m0b + e * 32;
    for (int i = tid; i < 64 * 32; i += 256) {
        int g = i >> 5, c = i & 31;
        float a = B0[c];
        for (int f = 0; f < 64; ++f) a += P[g * 64 + f] * W0[f * 32 + c];
        A1[i] = a > 0.f ? a : (__expf(a) - 1.f);
    }
    __syncthreads();
    fp W1 = m1W + e * 32 * 16; fp B1 = m1b + e * 16;
    for (int i = tid; i < 64 * 16; i += 256) {
        int g = i >> 4, c = i & 15;
        float a = B1[c];
        for (int f = 0; f < 32; ++f) a += A1[g * 32 + f] * W1[f * 16 + c];
        A2[i] = a > 0.f ? a : (__expf(a) - 1.f);
    }
    __syncthreads();
    fp W2 = m2W + e * 16 * 8; fp B2 = m2b + e * 8;
    for (int i = tid; i < 64 * 8; i += 256) {
        int g = i >> 3, c = i & 7;
        float a = B2[c];
        for (int f = 0; f < 16; ++f) a += A2[g * 16 + f] * W2[f * 8 + c];
        A3[i] = a > 0.f ? a : (__expf(a) - 1.f);
    }
    __syncthreads();
    fp W3 = m3W + e * 8;
    if (tid < 64) {
        int g = tid;
        float a = m3b[e];
        for (int j = 0; j < 8; ++j) a += A3[g * 8 + j] * W3[j];
        out[g * 6 + e] = a;
    }
}

__global__ __launch_bounds__(64) void loss_kernel(const float* __restrict__ preds, fp y,
                                                  float* __restrict__ out) {
    int lane = threadIdx.x;
    float lsum = 0.f;
    if (lane < 6) {
        float acc = 0.f;
        for (int g = 0; g < 64; ++g) {
            float d = preds[g * 6 + lane] - y[g * 6 + lane];
            acc += d * d;
        }
        lsum = sqrtf(acc / 64.f);
    }
#pragma unroll
    for (int off = 32; off; off >>= 1) lsum += __shfl_xor(lsum, off);
    if (lane == 0) out[384] = lsum;
}

extern "C" void kernel_launch(void* const* d_in, const int* in_sizes, int n_in, void* d_out, int out_size,
                              void* d_ws, size_t ws_size, hipStream_t stream) {
    bool dictOrder = (in_sizes[1] == 2 * N_EDGES);
    int iEI = dictOrder ? 1 : 33;
    int iEA = dictOrder ? 2 : 1;
    int iBT = dictOrder ? 3 : 34;
    int iY  = dictOrder ? 4 : 2;
    int w0  = dictOrder ? 5 : 3;

    fp x = (fp)d_in[0];
    const int* ei = (const int*)d_in[iEI];
    fp eattr = (fp)d_in[iEA];
    const int* batch = (const int*)d_in[iBT];
    fp y = (fp)d_in[iY];
    fp Wq0 = (fp)d_in[w0 + 0], bq0 = (fp)d_in[w0 + 1], Wk0 = (fp)d_in[w0 + 2], bk0 = (fp)d_in[w0 + 3];
    fp Wv0 = (fp)d_in[w0 + 4], bv0 = (fp)d_in[w0 + 5], We0 = (fp)d_in[w0 + 6];
    fp Ws0 = (fp)d_in[w0 + 7], bs0 = (fp)d_in[w0 + 8];
    fp Wq = (fp)d_in[w0 + 9], bq = (fp)d_in[w0 + 10], Wk = (fp)d_in[w0 + 11], bk = (fp)d_in[w0 + 12];
    fp Wv = (fp)d_in[w0 + 13], bv = (fp)d_in[w0 + 14], Wel = (fp)d_in[w0 + 15];
    fp Ws = (fp)d_in[w0 + 16], bs = (fp)d_in[w0 + 17];
    fp g1W = (fp)d_in[w0 + 18], g1b = (fp)d_in[w0 + 19], g2W = (fp)d_in[w0 + 20], g2b = (fp)d_in[w0 + 21];
    fp m0W = (fp)d_in[w0 + 22], m0b = (fp)d_in[w0 + 23], m1W = (fp)d_in[w0 + 24], m1b = (fp)d_in[w0 + 25];
    fp m2W = (fp)d_in[w0 + 26], m2b = (fp)d_in[w0 + 27], m3W = (fp)d_in[w0 + 28], m3b = (fp)d_in[w0 + 29];

    const int* srcArr = ei;
    const int* dstArr = ei + N_EDGES;

    char* wsp = (char*)d_ws;
    auto alloc = [&](size_t bytes) -> void* {
        void* p = (void*)wsp;
        wsp += (bytes + 255) & ~(size_t)255;
        return p;
    };
    u16* qb = (u16*)alloc((size_t)N_NODES * 64 * 2);         // bf16, prescaled 1/8
    u32* kvp = (u32*)alloc((size_t)N_NODES * 64 * 4);        // packed bf16 k|v<<16 per feature
    u16* skbb = (u16*)alloc((size_t)N_NODES * 64 * 2);       // bf16 skip
    u16* hb = (u16*)alloc((size_t)N_NODES * 64 * 2);         // h bf16 (gemm A for layers 1-3)
    u16* xb = (u16*)alloc((size_t)N_NODES * IN_CH * 2);      // x bf16
    u16* hmaxb = (u16*)alloc((size_t)N_NODES * 64 * 2);      // JK max, bf16
    float* gate = (float*)alloc((size_t)N_NODES * 4);
    float* pooled = (float*)alloc(64 * 64 * 4);
    u32* gmaxEnc = (u32*)alloc(N_GRAPHS * 4);
    float* gsum = (float*)alloc(N_GRAPHS * 4);
    int* row_ptr = (int*)alloc((N_NODES + 1) * 4);
    int* cursor = (int*)alloc((size_t)N_NODES * 4);
    int* csr_src = (int*)alloc((size_t)N_EDGES * 4);
    uint4* eab = (uint4*)alloc((size_t)N_EDGES * 16);
    u16* Bp0 = (u16*)alloc((size_t)(IN_CH / 32) * 16 * 512 * 2);
    u16* Bp1 = (u16*)alloc((size_t)(DIM / 32) * 16 * 512 * 2);
    u16* Bp2 = (u16*)alloc((size_t)(DIM / 32) * 16 * 512 * 2);
    u16* Bp3 = (u16*)alloc((size_t)(DIM / 32) * 16 * 512 * 2);
    int* blksum = (int*)alloc(256 * 4);
    (void)ws_size;
    (void)n_in;

    float* outF = (float*)d_out;  // [0..383] preds, [384] total_loss

    // ---- CSR build (by dst) + weight/x conversion ----
    hipMemsetAsync(cursor, 0, (size_t)N_NODES * 4, stream);
    hipMemsetAsync(gmaxEnc, 0, N_GRAPHS * 4, stream);
    hipMemsetAsync(gsum, 0, N_GRAPHS * 4, stream);
    hipMemsetAsync(pooled, 0, 64 * 64 * 4, stream);
    count_kernel<<<(N_EDGES + 255) / 256, 256, 0, stream>>>(dstArr, cursor);
    scan1_kernel<<<NBLK, 512, 0, stream>>>(cursor, row_ptr, blksum);
    scan2_kernel<<<1, 256, 0, stream>>>(blksum);
    scan3_kernel<<<NBLK, 512, 0, stream>>>(row_ptr, blksum, cursor);
    for (int p = 0; p < NPASS; ++p)
        scatter_pass_kernel<<<(N_EDGES + 255) / 256, 256, 0, stream>>>(
            srcArr, dstArr, eattr, cursor, csr_src, eab, p * PASS_SZ, (p + 1) * PASS_SZ);
    cvt_bf16_kernel<<<(N_NODES * IN_CH / 4 + 255) / 256, 256, 0, stream>>>(x, xb, N_NODES * IN_CH / 4);
    packW_kernel<<<((IN_CH / 32) * 16 * 512 + 255) / 256, 256, 0, stream>>>(Wq0, Wk0, Wv0, Ws0, Bp0, IN_CH);
    u16* Bps[3] = {Bp1, Bp2, Bp3};
    for (int i = 0; i < N_CONVS; ++i)
        packW_kernel<<<((DIM / 32) * 16 * 512 + 255) / 256, 256, 0, stream>>>(
            Wq + i * 4096, Wk + i * 4096, Wv + i * 4096, Ws + i * 4096, Bps[i], DIM);

    int nodeGrid = N_NODES / 4;  // 1 node per wave, 4 waves per block
    // layer 0 (conv_first, 128 -> 64), ELU, init hmax
    gemm_mfma_kernel<IN_CH><<<N_NODES / 32, 256, 0, stream>>>(xb, Bp0, bq0, bk0, bv0, bs0, qb, kvp, skbb);
    node_kernel<<<nodeGrid, 256, 0, stream>>>(qb, kvp, skbb, eab, We0, row_ptr, csr_src, hb, hmaxb, 1, 1);
    // layers 1..3 (64 -> 64); ELU except last; JK running max
    for (int i = 0; i < N_CONVS; ++i) {
        gemm_mfma_kernel<DIM><<<N_NODES / 32, 256, 0, stream>>>(hb, Bps[i], bq + i * 64, bk + i * 64,
                                                                bv + i * 64, bs + i * 64, qb, kvp, skbb);
        node_kernel<<<nodeGrid, 256, 0, stream>>>(qb, kvp, skbb, eab, Wel + i * 448, row_ptr,
                                                  csr_src, hb, hmaxb, (i < N_CONVS - 1) ? 1 : 0, 0);
    }
    // pooling head: gate -> segmented max -> exp/sum -> chunked accum -> MLP (divides by gsum)
    gate_kernel<<<N_NODES / 4, 256, 0, stream>>>(hmaxb, g1W, g1b, g2W, g2b, gate);
    gmax_kernel<<<(N_NODES + 255) / 256, 256, 0, stream>>>(gate, batch, gmaxEnc);
    expsum_kernel<<<(N_NODES + 255) / 256, 256, 0, stream>>>(batch, gmaxEnc, gate, gsum);
    pool_accum_kernel<<<(N_NODES + PCHUNK - 1) / PCHUNK, 256, 0, stream>>>(hmaxb, gate, batch, pooled);
    mlp_kernel<<<6, 256, 0, stream>>>(pooled, gsum, m0W, m0b, m1W, m1b, m2W, m2b, m3W, m3b, outF);
    loss_kernel<<<1, 64, 0, stream>>>(outF, y, outF);
}

// Round 19
// 781.913 us; speedup vs baseline: 1.1185x; 1.1185x over previous
//
#include <hip/hip_runtime.h>
#include <math.h>

#define N_NODES 100000
#define N_EDGES 1600000
#define N_GRAPHS 64
#define IN_CH 128
#define DIM 64
#define N_CONVS 3
#define NBLK 196      // ceil(100000/512)
#define NPASS 8
#define PASS_SZ 12500  // N_NODES / NPASS

typedef const float* fp;
typedef unsigned int u32;
typedef unsigned short u16;
typedef __attribute__((ext_vector_type(8))) short short8v;
typedef __attribute__((ext_vector_type(4))) float f32x4;

__device__ inline u16 rne_bf16(float f) {
    u32 u = __float_as_uint(f);
    return (u16)((u + 0x7fffu + ((u >> 16) & 1u)) >> 16);
}
__device__ inline float bf16_f(u16 w) { return __uint_as_float((u32)w << 16); }
__device__ inline float bf16lo_f(u32 w) { return __uint_as_float(w << 16); }
__device__ inline float bf16hi_f(u32 w) { return __uint_as_float(w & 0xffff0000u); }
// order-preserving float <-> uint encoding (for atomicMax on floats incl. negatives)
__device__ inline u32 f_enc(float f) {
    u32 u = __float_as_uint(f);
    return (u & 0x80000000u) ? ~u : (u | 0x80000000u);
}
__device__ inline float f_dec(u32 e) {
    u32 u = (e & 0x80000000u) ? (e & 0x7fffffffu) : ~e;
    return __uint_as_float(u);
}

// ---------------- CSR build ----------------
__global__ __launch_bounds__(256) void count_kernel(const int* __restrict__ dst, int* __restrict__ cnt) {
    int j = blockIdx.x * 256 + threadIdx.x;
    if (j < N_EDGES) {
        int d = dst[j];
        if ((unsigned)d < N_NODES) atomicAdd(&cnt[d], 1);
    }
}

__global__ __launch_bounds__(512) void scan1_kernel(const int* __restrict__ cnt, int* __restrict__ rp,
                                                    int* __restrict__ blksum) {
    __shared__ int tmp[512];
    int t = threadIdx.x, i = blockIdx.x * 512 + t;
    int v0 = (i < N_NODES) ? cnt[i] : 0;
    tmp[t] = v0;
    __syncthreads();
    for (int off = 1; off < 512; off <<= 1) {
        int add = (t >= off) ? tmp[t - off] : 0;
        __syncthreads();
        tmp[t] += add;
        __syncthreads();
    }
    if (i < N_NODES) rp[i] = tmp[t] - v0;
    if (t == 511) blksum[blockIdx.x] = tmp[511];
}

__global__ __launch_bounds__(256) void scan2_kernel(int* __restrict__ blksum) {
    __shared__ int tmp[256];
    int t = threadIdx.x;
    int v0 = (t < NBLK) ? blksum[t] : 0;
    tmp[t] = v0;
    __syncthreads();
    for (int off = 1; off < 256; off <<= 1) {
        int add = (t >= off) ? tmp[t - off] : 0;
        __syncthreads();
        tmp[t] += add;
        __syncthreads();
    }
    if (t < NBLK) blksum[t] = tmp[t] - v0;
}

__global__ __launch_bounds__(512) void scan3_kernel(int* __restrict__ rp, const int* __restrict__ blksum,
                                                    int* __restrict__ cursor) {
    int t = threadIdx.x, i = blockIdx.x * 512 + t;
    if (i < N_NODES) {
        int v = rp[i] + blksum[blockIdx.x];
        rp[i] = v;
        cursor[i] = v;
    }
    if (i == 0) rp[N_NODES] = N_EDGES;
}

// range-split scatter with inline ea->bf16 pack: only edges with dst in [lo, hi)
__global__ __launch_bounds__(256) void scatter_pass_kernel(const int* __restrict__ src,
                                                           const int* __restrict__ dst, fp ea,
                                                           int* __restrict__ cursor,
                                                           int* __restrict__ csr_src,
                                                           uint4* __restrict__ eab, int lo, int hi) {
    int j = blockIdx.x * 256 + threadIdx.x;
    if (j < N_EDGES) {
        int d = dst[j];
        if (d < lo || d >= hi || (unsigned)d >= N_NODES) return;
        int pos = atomicAdd(&cursor[d], 1);
        if ((unsigned)pos < N_EDGES) {
            int s = src[j];
            csr_src[pos] = ((unsigned)s < N_NODES) ? s : 0;
            size_t sb = (size_t)j * 7;
            u16 b[8];
#pragma unroll
            for (int c = 0; c < 7; ++c) b[c] = rne_bf16(ea[sb + c]);
            b[7] = 0;
            uint4 o;
            o.x = b[0] | ((u32)b[1] << 16);
            o.y = b[2] | ((u32)b[3] << 16);
            o.z = b[4] | ((u32)b[5] << 16);
            o.w = b[6] | ((u32)b[7] << 16);
            eab[pos] = o;
        }
    }
}

// ---------------- x -> bf16 ----------------
__global__ __launch_bounds__(256) void cvt_bf16_kernel(const float* __restrict__ in, u16* __restrict__ out,
                                                       int n4) {
    int i = blockIdx.x * 256 + threadIdx.x;
    if (i < n4) {
        float4 v = reinterpret_cast<const float4*>(in)[i];
        ushort4 o;
        o.x = rne_bf16(v.x); o.y = rne_bf16(v.y); o.z = rne_bf16(v.z); o.w = rne_bf16(v.w);
        reinterpret_cast<ushort4*>(out)[i] = o;
    }
}

// ---------------- pack W (q|k|v|s -> K x 256) into MFMA B-fragment order ----------------
__global__ __launch_bounds__(256) void packW_kernel(fp Wq, fp Wk, fp Wv, fp Ws, u16* __restrict__ Bp,
                                                    int K) {
    int total = (K / 32) * 16 * 512;
    int tid = blockIdx.x * 256 + threadIdx.x;
    if (tid >= total) return;
    int j = tid & 7, l = (tid >> 3) & 63, fragid = tid >> 9;
    int tk = fragid >> 4, gtn = fragid & 15;
    int k = tk * 32 + ((l >> 4) << 3) + j;
    int n = (gtn << 4) + (l & 15);
    int mat = n >> 6, cn = n & 63;
    fp W = mat == 0 ? Wq : mat == 1 ? Wk : mat == 2 ? Wv : Ws;
    Bp[tid] = rne_bf16(W[k * 64 + cn]);
}

// ---------------- fused MFMA GEMM: q(bf16, *1/8) | kv(dense u32 via LDS pack) | skip(bf16) ----------------
template <int K>
__global__ __launch_bounds__(256) void gemm_mfma_kernel(
    const u16* __restrict__ A, const u16* __restrict__ Bp,
    fp bq, fp bk, fp bv, fp bs,
    u16* __restrict__ qb, u32* __restrict__ kvp, u16* __restrict__ skbb) {
    constexpr int NTK = K / 32;
    __shared__ u16 kls[32][64];
    int wave = threadIdx.x >> 6;  // 0:q 1:k 2:v 3:skip
    int l = threadIdx.x & 63;
    int lr = l & 15, lg = l >> 4;
    int row0 = blockIdx.x * 32;
    short8v a[2][NTK];
#pragma unroll
    for (int mi = 0; mi < 2; ++mi)
#pragma unroll
        for (int tk = 0; tk < NTK; ++tk)
            a[mi][tk] = *reinterpret_cast<const short8v*>(
                &A[(size_t)(row0 + mi * 16 + lr) * K + tk * 32 + lg * 8]);
    f32x4 c[2][4] = {};
#pragma unroll
    for (int tn = 0; tn < 4; ++tn) {
        int gtn = wave * 4 + tn;
#pragma unroll
        for (int tk = 0; tk < NTK; ++tk) {
            short8v b = *reinterpret_cast<const short8v*>(&Bp[((size_t)(tk * 16 + gtn) * 64 + l) * 8]);
            c[0][tn] = __builtin_amdgcn_mfma_f32_16x16x32_bf16(a[0][tk], b, c[0][tn], 0, 0, 0);
            c[1][tn] = __builtin_amdgcn_mfma_f32_16x16x32_bf16(a[1][tk], b, c[1][tn], 0, 0, 0);
        }
    }
    fp bias = wave == 0 ? bq : wave == 1 ? bk : wave == 2 ? bv : bs;
    if (wave == 1) {  // stage k into LDS
#pragma unroll
        for (int tn = 0; tn < 4; ++tn) {
            int cl = tn * 16 + lr;
            float bb = bias[cl];
#pragma unroll
            for (int mi = 0; mi < 2; ++mi)
#pragma unroll
                for (int r = 0; r < 4; ++r) {
                    int rr = mi * 16 + lg * 4 + r;
                    kls[rr][cl] = rne_bf16(c[mi][tn][r] + bb);
                }
        }
    }
    __syncthreads();
    if (wave == 1) return;
#pragma unroll
    for (int tn = 0; tn < 4; ++tn) {
        int cl = tn * 16 + lr;
        float bb = bias[cl];
#pragma unroll
        for (int mi = 0; mi < 2; ++mi)
#pragma unroll
            for (int r = 0; r < 4; ++r) {
                int rr = mi * 16 + lg * 4 + r;
                size_t row = row0 + rr;
                float val = c[mi][tn][r] + bb;
                if (wave == 0) qb[row * 64 + cl] = rne_bf16(val * 0.125f);
                else if (wave == 3) skbb[row * 64 + cl] = rne_bf16(val);
                else kvp[row * 64 + cl] = (u32)kls[rr][cl] | ((u32)rne_bf16(val) << 16);
            }
    }
}

// ---------------- per-node edge aggregation: 4 nodes/wave, 16 lanes/node, e-channel-per-lane ----------------
__global__ __launch_bounds__(256) void node_kernel(
    const u16* __restrict__ qb, const u32* __restrict__ kvp,
    const u16* __restrict__ skbb, const uint4* __restrict__ eab, fp We,
    const int* __restrict__ row_ptr, const int* __restrict__ csr_src,
    u16* __restrict__ hb, u16* __restrict__ hmaxb, int act, int initmax) {
    int tid = threadIdx.x;
    int lane = tid & 63;
    int g = lane >> 4, fl = lane & 15;
    int gbase = g << 4;
    int n = blockIdx.x * 16 + (tid >> 6) * 4 + g;
    int f0 = fl * 4;
    ushort4 qv = *reinterpret_cast<const ushort4*>(&qb[(size_t)n * 64 + f0]);
    float4 q4;
    q4.x = bf16_f(qv.x); q4.y = bf16_f(qv.y); q4.z = bf16_f(qv.z); q4.w = bf16_f(qv.w);
    // qw_own: lane fl (fl<7) keeps qw[fl] = sum_f q[f]*We[fl][f]; other lanes 0
    float qw_own = 0.f;
#pragma unroll
    for (int c = 0; c < 7; ++c) {
        float4 w4 = *reinterpret_cast<const float4*>(&We[c * 64 + f0]);
        float t = q4.x * w4.x + q4.y * w4.y + q4.z * w4.z + q4.w * w4.w;
        t += __shfl_xor(t, 1);
        t += __shfl_xor(t, 2);
        t += __shfl_xor(t, 4);
        t += __shfl_xor(t, 8);
        if (fl == c) qw_own = t;
    }
    int beg = row_ptr[n], end = row_ptr[n + 1];
    float s = 0.f;
    float ax = 0.f, ay = 0.f, az = 0.f, aw = 0.f;
    float r_own = 0.f;  // sum pe * ea[fl]  (lane's channel)

    for (int p = beg; p < end; p += 4) {
        int svi = p + (fl & 3);
        svi = svi < end ? svi : end - 1;
        int sv = csr_src[svi];
#pragma unroll
        for (int j = 0; j < 4; ++j) {
            int pj = p + j;
            int pc = pj < end ? pj : end - 1;
            int sn = __shfl(sv, gbase + j);
            uint4 kv4 = *reinterpret_cast<const uint4*>(&kvp[(size_t)sn * 64 + f0]);
            uint4 e4 = eab[pc];
            // lane's edge-attr channel (fl<7 valid; fl==7 -> packed 0; fl>=8 garbage but unused)
            u32 w01 = (fl & 2) ? e4.y : e4.x;
            u32 w23 = (fl & 2) ? e4.w : e4.z;
            u32 wsel = (fl & 4) ? w23 : w01;
            float e_own = (fl & 1) ? bf16hi_f(wsel) : bf16lo_f(wsel);
            float kf0 = bf16lo_f(kv4.x), vf0 = bf16hi_f(kv4.x);
            float kf1 = bf16lo_f(kv4.y), vf1 = bf16hi_f(kv4.y);
            float kf2 = bf16lo_f(kv4.z), vf2 = bf16hi_f(kv4.z);
            float kf3 = bf16lo_f(kv4.w), vf3 = bf16hi_f(kv4.w);
            // fused alpha: butterfly over (q.k partials + qw[fl]*ea[fl])
            float d = q4.x * kf0 + q4.y * kf1 + q4.z * kf2 + q4.w * kf3 + qw_own * e_own;
            d += __shfl_xor(d, 1);
            d += __shfl_xor(d, 2);
            d += __shfl_xor(d, 4);
            d += __shfl_xor(d, 8);
            float pe = (pj < end) ? __expf(d) : 0.f;
            s += pe;
            ax += pe * vf0; ay += pe * vf1; az += pe * vf2; aw += pe * vf3;
            r_own += pe * e_own;
        }
    }
    float inv = 1.f / (s + 1e-16f);
    float o0 = ax, o1 = ay, o2 = az, o3 = aw;
#pragma unroll
    for (int c = 0; c < 7; ++c) {
        float rc = __shfl(r_own, gbase + c);
        o0 += We[c * 64 + f0 + 0] * rc;
        o1 += We[c * 64 + f0 + 1] * rc;
        o2 += We[c * 64 + f0 + 2] * rc;
        o3 += We[c * 64 + f0 + 3] * rc;
    }
    ushort4 skv = *reinterpret_cast<const ushort4*>(&skbb[(size_t)n * 64 + f0]);
    float4 res;
    res.x = o0 * inv + bf16_f(skv.x);
    res.y = o1 * inv + bf16_f(skv.y);
    res.z = o2 * inv + bf16_f(skv.z);
    res.w = o3 * inv + bf16_f(skv.w);
    if (act) {
        res.x = res.x > 0.f ? res.x : (__expf(res.x) - 1.f);
        res.y = res.y > 0.f ? res.y : (__expf(res.y) - 1.f);
        res.z = res.z > 0.f ? res.z : (__expf(res.z) - 1.f);
        res.w = res.w > 0.f ? res.w : (__expf(res.w) - 1.f);
    }
    ushort4 hb4;
    hb4.x = rne_bf16(res.x); hb4.y = rne_bf16(res.y); hb4.z = rne_bf16(res.z); hb4.w = rne_bf16(res.w);
    *reinterpret_cast<ushort4*>(&hb[(size_t)n * 64 + f0]) = hb4;
    if (initmax) {
        *reinterpret_cast<ushort4*>(&hmaxb[(size_t)n * 64 + f0]) = hb4;
    } else {
        ushort4 hm4 = *reinterpret_cast<const ushort4*>(&hmaxb[(size_t)n * 64 + f0]);
        hm4.x = rne_bf16(fmaxf(bf16_f(hm4.x), res.x));
        hm4.y = rne_bf16(fmaxf(bf16_f(hm4.y), res.y));
        hm4.z = rne_bf16(fmaxf(bf16_f(hm4.z), res.z));
        hm4.w = rne_bf16(fmaxf(bf16_f(hm4.w), res.w));
        *reinterpret_cast<ushort4*>(&hmaxb[(size_t)n * 64 + f0]) = hm4;
    }
}

// ---------------- gate MLP per node (bf16 hmax input, no atomics) ----------------
__global__ __launch_bounds__(256) void gate_kernel(const u16* __restrict__ h, fp g1W, fp g1b, fp g2W,
                                                   fp g2b, float* __restrict__ gate) {
    __shared__ float hs[4][64];
    int w = threadIdx.x >> 6, lane = threadIdx.x & 63;
    int n = blockIdx.x * 4 + w;
    hs[w][lane] = bf16_f(h[(size_t)n * 64 + lane]);
    __syncthreads();
    float a = 0.f;
    for (int f = 0; f < 64; ++f) a += hs[w][f] * g1W[f * 64 + lane];
    a = fmaxf(a + g1b[lane], 0.f);
    float val = a * g2W[lane];
#pragma unroll
    for (int off = 32; off; off >>= 1) val += __shfl_xor(val, off);
    if (lane == 0) gate[n] = val + g2b[0];
}

// per-graph max via wave-segmented atomicMax (~1600 atomics total)
__global__ __launch_bounds__(256) void gmax_kernel(const float* __restrict__ gate,
                                                   const int* __restrict__ batch,
                                                   u32* __restrict__ gmaxEnc) {
    int i = blockIdx.x * 256 + threadIdx.x;
    if (i >= N_NODES) return;
    int lane = threadIdx.x & 63;
    int g = batch[i];
    u32 e = f_enc(gate[i]);
    int waveBase = i - lane;
    if (waveBase + 63 < N_NODES) {
        int g0 = __shfl(g, 0), g63 = __shfl(g, 63);
        if (g0 == g63) {
            u32 t = e;
#pragma unroll
            for (int off = 32; off; off >>= 1) t = max(t, (u32)__shfl_xor((int)t, off));
            if (lane == 0) atomicMax(&gmaxEnc[g], t);
            return;
        }
    }
    atomicMax(&gmaxEnc[g], e);
}

// exp + per-graph sum; overwrites gate[i] with exp(gate-m)
__global__ __launch_bounds__(256) void expsum_kernel(const int* __restrict__ batch,
                                                     const u32* __restrict__ gmaxEnc,
                                                     float* __restrict__ gate, float* __restrict__ gsum) {
    int i = blockIdx.x * 256 + threadIdx.x;
    if (i >= N_NODES) return;
    int lane = threadIdx.x & 63;
    int g = batch[i];
    float p = __expf(gate[i] - f_dec(gmaxEnc[g]));
    gate[i] = p;
    int waveBase = i - lane;
    bool fullWave = (waveBase + 63 < N_NODES);
    if (fullWave) {
        int g0 = __shfl(g, 0), g63 = __shfl(g, 63);
        if (g0 == g63) {
            float t = p;
#pragma unroll
            for (int off = 32; off; off >>= 1) t += __shfl_xor(t, off);
            if (lane == 0) atomicAdd(&gsum[g], t);
            return;
        }
    }
    atomicAdd(&gsum[g], p);
}

// chunked weighted accumulation: pooled[g][f] += gate[i] * h[i][f]  (bf16 h)
#define PCHUNK 256
__global__ __launch_bounds__(256) void pool_accum_kernel(const u16* __restrict__ h,
                                                         const float* __restrict__ gate,
                                                         const int* __restrict__ batch,
                                                         float* __restrict__ pooled) {
    int w = threadIdx.x >> 6, lane = threadIdx.x & 63;
    int base = blockIdx.x * PCHUNK;
    float acc = 0.f;
    int cur = -1;
    for (int t = 0; t < PCHUNK / 4; ++t) {
        int i = base + w + 4 * t;
        if (i >= N_NODES) break;
        int g = batch[i];
        if (g != cur) {
            if (cur >= 0) atomicAdd(&pooled[cur * 64 + lane], acc);
            acc = 0.f;
            cur = g;
        }
        acc += gate[i] * bf16_f(h[(size_t)i * 64 + lane]);
    }
    if (cur >= 0) atomicAdd(&pooled[cur * 64 + lane], acc);
}

// ---------------- 6-expert MLP head (f32 output); divides pooled by gsum ----------------
__global__ __launch_bounds__(256) void mlp_kernel(const float* __restrict__ pooled,
                                                  const float* __restrict__ gsum, fp m0W, fp m0b, fp m1W,
                                                  fp m1b, fp m2W, fp m2b, fp m3W, fp m3b,
                                                  float* __restrict__ out) {
    int e = blockIdx.x, tid = threadIdx.x;
    __shared__ float P[64 * 64];
    __shared__ float A1[64 * 32];
    __shared__ float A2[64 * 16];
    __shared__ float A3[64 * 8];
    for (int i = tid; i < 64 * 64; i += 256) P[i] = pooled[i] / (gsum[i >> 6] + 1e-16f);
    __syncthreads();
    fp W0 = m0W + e * 64 * 32; fp B0 = m0b + e * 32;
    for (int i = tid; i < 64 * 32; i += 256) {
        int g = i >> 5, c = i & 31;
        float a = B0[c];
        for (int f = 0; f < 64; ++f) a += P[g * 64 + f] * W0[f * 32 + c];
        A1[i] = a > 0.f ? a : (__expf(a) - 1.f);
    }
    __syncthreads();
    fp W1 = m1W + e * 32 * 16; fp B1 = m1b + e * 16;
    for (int i = tid; i < 64 * 16; i += 256) {
        int g = i >> 4, c = i & 15;
        float a = B1[c];
        for (int f = 0; f < 32; ++f) a += A1[g * 32 + f] * W1[f * 16 + c];
        A2[i] = a > 0.f ? a : (__expf(a) - 1.f);
    }
    __syncthreads();
    fp W2 = m2W + e * 16 * 8; fp B2 = m2b + e * 8;
    for (int i = tid; i < 64 * 8; i += 256) {
        int g = i >> 3, c = i & 7;
        float a = B2[c];
        for (int f = 0; f < 16; ++f) a += A2[g * 16 + f] * W2[f * 8 + c];
        A3[i] = a > 0.f ? a : (__expf(a) - 1.f);
    }
    __syncthreads();
    fp W3 = m3W + e * 8;
    if (tid < 64) {
        int g = tid;
        float a = m3b[e];
        for (int j = 0; j < 8; ++j) a += A3[g * 8 + j] * W3[j];
        out[g * 6 + e] = a;
    }
}

__global__ __launch_bounds__(64) void loss_kernel(const float* __restrict__ preds, fp y,
                                                  float* __restrict__ out) {
    int lane = threadIdx.x;
    float lsum = 0.f;
    if (lane < 6) {
        float acc = 0.f;
        for (int g = 0; g < 64; ++g) {
            float d = preds[g * 6 + lane] - y[g * 6 + lane];
            acc += d * d;
        }
        lsum = sqrtf(acc / 64.f);
    }
#pragma unroll
    for (int off = 32; off; off >>= 1) lsum += __shfl_xor(lsum, off);
    if (lane == 0) out[384] = lsum;
}

extern "C" void kernel_launch(void* const* d_in, const int* in_sizes, int n_in, void* d_out, int out_size,
                              void* d_ws, size_t ws_size, hipStream_t stream) {
    bool dictOrder = (in_sizes[1] == 2 * N_EDGES);
    int iEI = dictOrder ? 1 : 33;
    int iEA = dictOrder ? 2 : 1;
    int iBT = dictOrder ? 3 : 34;
    int iY  = dictOrder ? 4 : 2;
    int w0  = dictOrder ? 5 : 3;

    fp x = (fp)d_in[0];
    const int* ei = (const int*)d_in[iEI];
    fp eattr = (fp)d_in[iEA];
    const int* batch = (const int*)d_in[iBT];
    fp y = (fp)d_in[iY];
    fp Wq0 = (fp)d_in[w0 + 0], bq0 = (fp)d_in[w0 + 1], Wk0 = (fp)d_in[w0 + 2], bk0 = (fp)d_in[w0 + 3];
    fp Wv0 = (fp)d_in[w0 + 4], bv0 = (fp)d_in[w0 + 5], We0 = (fp)d_in[w0 + 6];
    fp Ws0 = (fp)d_in[w0 + 7], bs0 = (fp)d_in[w0 + 8];
    fp Wq = (fp)d_in[w0 + 9], bq = (fp)d_in[w0 + 10], Wk = (fp)d_in[w0 + 11], bk = (fp)d_in[w0 + 12];
    fp Wv = (fp)d_in[w0 + 13], bv = (fp)d_in[w0 + 14], Wel = (fp)d_in[w0 + 15];
    fp Ws = (fp)d_in[w0 + 16], bs = (fp)d_in[w0 + 17];
    fp g1W = (fp)d_in[w0 + 18], g1b = (fp)d_in[w0 + 19], g2W = (fp)d_in[w0 + 20], g2b = (fp)d_in[w0 + 21];
    fp m0W = (fp)d_in[w0 + 22], m0b = (fp)d_in[w0 + 23], m1W = (fp)d_in[w0 + 24], m1b = (fp)d_in[w0 + 25];
    fp m2W = (fp)d_in[w0 + 26], m2b = (fp)d_in[w0 + 27], m3W = (fp)d_in[w0 + 28], m3b = (fp)d_in[w0 + 29];

    const int* srcArr = ei;
    const int* dstArr = ei + N_EDGES;

    char* wsp = (char*)d_ws;
    auto alloc = [&](size_t bytes) -> void* {
        void* p = (void*)wsp;
        wsp += (bytes + 255) & ~(size_t)255;
        return p;
    };
    u16* qb = (u16*)alloc((size_t)N_NODES * 64 * 2);         // bf16, prescaled 1/8
    u32* kvp = (u32*)alloc((size_t)N_NODES * 64 * 4);        // packed bf16 k|v<<16 per feature
    u16* skbb = (u16*)alloc((size_t)N_NODES * 64 * 2);       // bf16 skip
    u16* hb = (u16*)alloc((size_t)N_NODES * 64 * 2);         // h bf16 (gemm A for layers 1-3)
    u16* xb = (u16*)alloc((size_t)N_NODES * IN_CH * 2);      // x bf16
    u16* hmaxb = (u16*)alloc((size_t)N_NODES * 64 * 2);      // JK max, bf16
    float* gate = (float*)alloc((size_t)N_NODES * 4);
    float* pooled = (float*)alloc(64 * 64 * 4);
    u32* gmaxEnc = (u32*)alloc(N_GRAPHS * 4);
    float* gsum = (float*)alloc(N_GRAPHS * 4);
    int* row_ptr = (int*)alloc((N_NODES + 1) * 4);
    int* cursor = (int*)alloc((size_t)N_NODES * 4);
    int* csr_src = (int*)alloc((size_t)N_EDGES * 4);
    uint4* eab = (uint4*)alloc((size_t)N_EDGES * 16);
    u16* Bp0 = (u16*)alloc((size_t)(IN_CH / 32) * 16 * 512 * 2);
    u16* Bp1 = (u16*)alloc((size_t)(DIM / 32) * 16 * 512 * 2);
    u16* Bp2 = (u16*)alloc((size_t)(DIM / 32) * 16 * 512 * 2);
    u16* Bp3 = (u16*)alloc((size_t)(DIM / 32) * 16 * 512 * 2);
    int* blksum = (int*)alloc(256 * 4);
    (void)ws_size;
    (void)n_in;

    float* outF = (float*)d_out;  // [0..383] preds, [384] total_loss

    // ---- CSR build (by dst) + weight/x conversion ----
    hipMemsetAsync(cursor, 0, (size_t)N_NODES * 4, stream);
    hipMemsetAsync(gmaxEnc, 0, N_GRAPHS * 4, stream);
    hipMemsetAsync(gsum, 0, N_GRAPHS * 4, stream);
    hipMemsetAsync(pooled, 0, 64 * 64 * 4, stream);
    count_kernel<<<(N_EDGES + 255) / 256, 256, 0, stream>>>(dstArr, cursor);
    scan1_kernel<<<NBLK, 512, 0, stream>>>(cursor, row_ptr, blksum);
    scan2_kernel<<<1, 256, 0, stream>>>(blksum);
    scan3_kernel<<<NBLK, 512, 0, stream>>>(row_ptr, blksum, cursor);
    for (int p = 0; p < NPASS; ++p)
        scatter_pass_kernel<<<(N_EDGES + 255) / 256, 256, 0, stream>>>(
            srcArr, dstArr, eattr, cursor, csr_src, eab, p * PASS_SZ, (p + 1) * PASS_SZ);
    cvt_bf16_kernel<<<(N_NODES * IN_CH / 4 + 255) / 256, 256, 0, stream>>>(x, xb, N_NODES * IN_CH / 4);
    packW_kernel<<<((IN_CH / 32) * 16 * 512 + 255) / 256, 256, 0, stream>>>(Wq0, Wk0, Wv0, Ws0, Bp0, IN_CH);
    u16* Bps[3] = {Bp1, Bp2, Bp3};
    for (int i = 0; i < N_CONVS; ++i)
        packW_kernel<<<((DIM / 32) * 16 * 512 + 255) / 256, 256, 0, stream>>>(
            Wq + i * 4096, Wk + i * 4096, Wv + i * 4096, Ws + i * 4096, Bps[i], DIM);

    int nodeGrid = N_NODES / 16;  // 4 nodes per wave, 4 waves per block
    // layer 0 (conv_first, 128 -> 64), ELU, init hmax
    gemm_mfma_kernel<IN_CH><<<N_NODES / 32, 256, 0, stream>>>(xb, Bp0, bq0, bk0, bv0, bs0, qb, kvp, skbb);
    node_kernel<<<nodeGrid, 256, 0, stream>>>(qb, kvp, skbb, eab, We0, row_ptr, csr_src, hb, hmaxb, 1, 1);
    // layers 1..3 (64 -> 64); ELU except last; JK running max
    for (int i = 0; i < N_CONVS; ++i) {
        gemm_mfma_kernel<DIM><<<N_NODES / 32, 256, 0, stream>>>(hb, Bps[i], bq + i * 64, bk + i * 64,
                                                                bv + i * 64, bs + i * 64, qb, kvp, skbb);
        node_kernel<<<nodeGrid, 256, 0, stream>>>(qb, kvp, skbb, eab, Wel + i * 448, row_ptr,
                                                  csr_src, hb, hmaxb, (i < N_CONVS - 1) ? 1 : 0, 0);
    }
    // pooling head: gate -> segmented max -> exp/sum -> chunked accum -> MLP (divides by gsum)
    gate_kernel<<<N_NODES / 4, 256, 0, stream>>>(hmaxb, g1W, g1b, g2W, g2b, gate);
    gmax_kernel<<<(N_NODES + 255) / 256, 256, 0, stream>>>(gate, batch, gmaxEnc);
    expsum_kernel<<<(N_NODES + 255) / 256, 256, 0, stream>>>(batch, gmaxEnc, gate, gsum);
    pool_accum_kernel<<<(N_NODES + PCHUNK - 1) / PCHUNK, 256, 0, stream>>>(hmaxb, gate, batch, pooled);
    mlp_kernel<<<6, 256, 0, stream>>>(pooled, gsum, m0W, m0b, m1W, m1b, m2W, m2b, m3W, m3b, outF);
    loss_kernel<<<1, 64, 0, stream>>>(outF, y, outF);
}

// Round 20
// 763.680 us; speedup vs baseline: 1.1452x; 1.0239x over previous
//
#include <hip/hip_runtime.h>
#include <math.h>

#define N_NODES 100000
#define N_EDGES 1600000
#define N_GRAPHS 64
#define IN_CH 128
#define DIM 64
#define N_CONVS 3
#define NBLK 196      // ceil(100000/512)
#define NPASS 8
#define PASS_SZ 12500  // N_NODES / NPASS

typedef const float* fp;
typedef unsigned int u32;
typedef unsigned short u16;
typedef __attribute__((ext_vector_type(8))) short short8v;
typedef __attribute__((ext_vector_type(4))) float f32x4;

__device__ inline u16 rne_bf16(float f) {
    u32 u = __float_as_uint(f);
    return (u16)((u + 0x7fffu + ((u >> 16) & 1u)) >> 16);
}
__device__ inline float bf16_f(u16 w) { return __uint_as_float((u32)w << 16); }
__device__ inline float bf16lo_f(u32 w) { return __uint_as_float(w << 16); }
__device__ inline float bf16hi_f(u32 w) { return __uint_as_float(w & 0xffff0000u); }
// order-preserving float <-> uint encoding (for atomicMax on floats incl. negatives)
__device__ inline u32 f_enc(float f) {
    u32 u = __float_as_uint(f);
    return (u & 0x80000000u) ? ~u : (u | 0x80000000u);
}
__device__ inline float f_dec(u32 e) {
    u32 u = (e & 0x80000000u) ? (e & 0x7fffffffu) : ~e;
    return __uint_as_float(u);
}

// ---------------- CSR build ----------------
__global__ __launch_bounds__(256) void count_kernel(const int* __restrict__ dst, int* __restrict__ cnt) {
    int j = blockIdx.x * 256 + threadIdx.x;
    if (j < N_EDGES) {
        int d = dst[j];
        if ((unsigned)d < N_NODES) atomicAdd(&cnt[d], 1);
    }
}

__global__ __launch_bounds__(512) void scan1_kernel(const int* __restrict__ cnt, int* __restrict__ rp,
                                                    int* __restrict__ blksum) {
    __shared__ int tmp[512];
    int t = threadIdx.x, i = blockIdx.x * 512 + t;
    int v0 = (i < N_NODES) ? cnt[i] : 0;
    tmp[t] = v0;
    __syncthreads();
    for (int off = 1; off < 512; off <<= 1) {
        int add = (t >= off) ? tmp[t - off] : 0;
        __syncthreads();
        tmp[t] += add;
        __syncthreads();
    }
    if (i < N_NODES) rp[i] = tmp[t] - v0;
    if (t == 511) blksum[blockIdx.x] = tmp[511];
}

__global__ __launch_bounds__(256) void scan2_kernel(int* __restrict__ blksum) {
    __shared__ int tmp[256];
    int t = threadIdx.x;
    int v0 = (t < NBLK) ? blksum[t] : 0;
    tmp[t] = v0;
    __syncthreads();
    for (int off = 1; off < 256; off <<= 1) {
        int add = (t >= off) ? tmp[t - off] : 0;
        __syncthreads();
        tmp[t] += add;
        __syncthreads();
    }
    if (t < NBLK) blksum[t] = tmp[t] - v0;
}

__global__ __launch_bounds__(512) void scan3_kernel(int* __restrict__ rp, const int* __restrict__ blksum,
                                                    int* __restrict__ cursor) {
    int t = threadIdx.x, i = blockIdx.x * 512 + t;
    if (i < N_NODES) {
        int v = rp[i] + blksum[blockIdx.x];
        rp[i] = v;
        cursor[i] = v;
    }
    if (i == 0) rp[N_NODES] = N_EDGES;
}

// range-split scatter with inline ea->bf16 pack: only edges with dst in [lo, hi)
__global__ __launch_bounds__(256) void scatter_pass_kernel(const int* __restrict__ src,
                                                           const int* __restrict__ dst, fp ea,
                                                           int* __restrict__ cursor,
                                                           int* __restrict__ csr_src,
                                                           uint4* __restrict__ eab, int lo, int hi) {
    int j = blockIdx.x * 256 + threadIdx.x;
    if (j < N_EDGES) {
        int d = dst[j];
        if (d < lo || d >= hi || (unsigned)d >= N_NODES) return;
        int pos = atomicAdd(&cursor[d], 1);
        if ((unsigned)pos < N_EDGES) {
            int s = src[j];
            csr_src[pos] = ((unsigned)s < N_NODES) ? s : 0;
            size_t sb = (size_t)j * 7;
            u16 b[8];
#pragma unroll
            for (int c = 0; c < 7; ++c) b[c] = rne_bf16(ea[sb + c]);
            b[7] = 0;
            uint4 o;
            o.x = b[0] | ((u32)b[1] << 16);
            o.y = b[2] | ((u32)b[3] << 16);
            o.z = b[4] | ((u32)b[5] << 16);
            o.w = b[6] | ((u32)b[7] << 16);
            eab[pos] = o;
        }
    }
}

// ---------------- x -> bf16 ----------------
__global__ __launch_bounds__(256) void cvt_bf16_kernel(const float* __restrict__ in, u16* __restrict__ out,
                                                       int n4) {
    int i = blockIdx.x * 256 + threadIdx.x;
    if (i < n4) {
        float4 v = reinterpret_cast<const float4*>(in)[i];
        ushort4 o;
        o.x = rne_bf16(v.x); o.y = rne_bf16(v.y); o.z = rne_bf16(v.z); o.w = rne_bf16(v.w);
        reinterpret_cast<ushort4*>(out)[i] = o;
    }
}

// ---------------- pack W (q|k|v|s -> K x 256) into MFMA B-fragment order ----------------
__global__ __launch_bounds__(256) void packW_kernel(fp Wq, fp Wk, fp Wv, fp Ws, u16* __restrict__ Bp,
                                                    int K) {
    int total = (K / 32) * 16 * 512;
    int tid = blockIdx.x * 256 + threadIdx.x;
    if (tid >= total) return;
    int j = tid & 7, l = (tid >> 3) & 63, fragid = tid >> 9;
    int tk = fragid >> 4, gtn = fragid & 15;
    int k = tk * 32 + ((l >> 4) << 3) + j;
    int n = (gtn << 4) + (l & 15);
    int mat = n >> 6, cn = n & 63;
    fp W = mat == 0 ? Wq : mat == 1 ? Wk : mat == 2 ? Wv : Ws;
    Bp[tid] = rne_bf16(W[k * 64 + cn]);
}

// ---------------- fused MFMA GEMM: q(bf16, *1/8) | kv(dense u32 via LDS pack) | skip(bf16) ----------------
template <int K>
__global__ __launch_bounds__(256) void gemm_mfma_kernel(
    const u16* __restrict__ A, const u16* __restrict__ Bp,
    fp bq, fp bk, fp bv, fp bs,
    u16* __restrict__ qb, u32* __restrict__ kvp, u16* __restrict__ skbb) {
    constexpr int NTK = K / 32;
    __shared__ u16 kls[32][64];
    int wave = threadIdx.x >> 6;  // 0:q 1:k 2:v 3:skip
    int l = threadIdx.x & 63;
    int lr = l & 15, lg = l >> 4;
    int row0 = blockIdx.x * 32;
    short8v a[2][NTK];
#pragma unroll
    for (int mi = 0; mi < 2; ++mi)
#pragma unroll
        for (int tk = 0; tk < NTK; ++tk)
            a[mi][tk] = *reinterpret_cast<const short8v*>(
                &A[(size_t)(row0 + mi * 16 + lr) * K + tk * 32 + lg * 8]);
    f32x4 c[2][4] = {};
#pragma unroll
    for (int tn = 0; tn < 4; ++tn) {
        int gtn = wave * 4 + tn;
#pragma unroll
        for (int tk = 0; tk < NTK; ++tk) {
            short8v b = *reinterpret_cast<const short8v*>(&Bp[((size_t)(tk * 16 + gtn) * 64 + l) * 8]);
            c[0][tn] = __builtin_amdgcn_mfma_f32_16x16x32_bf16(a[0][tk], b, c[0][tn], 0, 0, 0);
            c[1][tn] = __builtin_amdgcn_mfma_f32_16x16x32_bf16(a[1][tk], b, c[1][tn], 0, 0, 0);
        }
    }
    fp bias = wave == 0 ? bq : wave == 1 ? bk : wave == 2 ? bv : bs;
    if (wave == 1) {  // stage k into LDS
#pragma unroll
        for (int tn = 0; tn < 4; ++tn) {
            int cl = tn * 16 + lr;
            float bb = bias[cl];
#pragma unroll
            for (int mi = 0; mi < 2; ++mi)
#pragma unroll
                for (int r = 0; r < 4; ++r) {
                    int rr = mi * 16 + lg * 4 + r;
                    kls[rr][cl] = rne_bf16(c[mi][tn][r] + bb);
                }
        }
    }
    __syncthreads();
    if (wave == 1) return;
#pragma unroll
    for (int tn = 0; tn < 4; ++tn) {
        int cl = tn * 16 + lr;
        float bb = bias[cl];
#pragma unroll
        for (int mi = 0; mi < 2; ++mi)
#pragma unroll
            for (int r = 0; r < 4; ++r) {
                int rr = mi * 16 + lg * 4 + r;
                size_t row = row0 + rr;
                float val = c[mi][tn][r] + bb;
                if (wave == 0) qb[row * 64 + cl] = rne_bf16(val * 0.125f);
                else if (wave == 3) skbb[row * 64 + cl] = rne_bf16(val);
                else kvp[row * 64 + cl] = (u32)kls[rr][cl] | ((u32)rne_bf16(val) << 16);
            }
    }
}

// ---------------- per-node edge aggregation: 4 nodes/wave, 16 lanes/node, 8-edge batches ----------------
__global__ __launch_bounds__(256) void node_kernel(
    const u16* __restrict__ qb, const u32* __restrict__ kvp,
    const u16* __restrict__ skbb, const uint4* __restrict__ eab, fp We,
    const int* __restrict__ row_ptr, const int* __restrict__ csr_src,
    u16* __restrict__ hb, u16* __restrict__ hmaxb, int act, int initmax) {
    int tid = threadIdx.x;
    int lane = tid & 63;
    int g = lane >> 4, fl = lane & 15;
    int gbase = g << 4;
    int n = blockIdx.x * 16 + (tid >> 6) * 4 + g;
    int f0 = fl * 4;
    ushort4 qv = *reinterpret_cast<const ushort4*>(&qb[(size_t)n * 64 + f0]);
    float4 q4;
    q4.x = bf16_f(qv.x); q4.y = bf16_f(qv.y); q4.z = bf16_f(qv.z); q4.w = bf16_f(qv.w);
    // qw_own: lane fl (fl<7) keeps qw[fl] = sum_f q[f]*We[fl][f]; other lanes 0
    float qw_own = 0.f;
#pragma unroll
    for (int c = 0; c < 7; ++c) {
        float4 w4 = *reinterpret_cast<const float4*>(&We[c * 64 + f0]);
        float t = q4.x * w4.x + q4.y * w4.y + q4.z * w4.z + q4.w * w4.w;
        t += __shfl_xor(t, 1);
        t += __shfl_xor(t, 2);
        t += __shfl_xor(t, 4);
        t += __shfl_xor(t, 8);
        if (fl == c) qw_own = t;
    }
    int beg = row_ptr[n], end = row_ptr[n + 1];
    float s = 0.f;
    float ax = 0.f, ay = 0.f, az = 0.f, aw = 0.f;
    float r_own = 0.f;  // sum pe * ea[fl]  (lane's channel)

    for (int p = beg; p < end; p += 8) {
        int svi = p + (fl & 7);
        svi = svi < end ? svi : end - 1;
        int sv = csr_src[svi];
#pragma unroll
        for (int j = 0; j < 8; ++j) {
            int pj = p + j;
            int pc = pj < end ? pj : end - 1;
            int sn = __shfl(sv, gbase + j);
            uint4 kv4 = *reinterpret_cast<const uint4*>(&kvp[(size_t)sn * 64 + f0]);
            uint4 e4 = eab[pc];
            // lane's edge-attr channel (fl<7 valid; fl==7 -> packed 0; fl>=8 garbage but unused)
            u32 w01 = (fl & 2) ? e4.y : e4.x;
            u32 w23 = (fl & 2) ? e4.w : e4.z;
            u32 wsel = (fl & 4) ? w23 : w01;
            float e_own = (fl & 1) ? bf16hi_f(wsel) : bf16lo_f(wsel);
            float kf0 = bf16lo_f(kv4.x), vf0 = bf16hi_f(kv4.x);
            float kf1 = bf16lo_f(kv4.y), vf1 = bf16hi_f(kv4.y);
            float kf2 = bf16lo_f(kv4.z), vf2 = bf16hi_f(kv4.z);
            float kf3 = bf16lo_f(kv4.w), vf3 = bf16hi_f(kv4.w);
            // fused alpha: butterfly over (q.k partials + qw[fl]*ea[fl])
            float d = q4.x * kf0 + q4.y * kf1 + q4.z * kf2 + q4.w * kf3 + qw_own * e_own;
            d += __shfl_xor(d, 1);
            d += __shfl_xor(d, 2);
            d += __shfl_xor(d, 4);
            d += __shfl_xor(d, 8);
            float pe = (pj < end) ? __expf(d) : 0.f;
            s += pe;
            ax += pe * vf0; ay += pe * vf1; az += pe * vf2; aw += pe * vf3;
            r_own += pe * e_own;
        }
    }
    float inv = 1.f / (s + 1e-16f);
    float o0 = ax, o1 = ay, o2 = az, o3 = aw;
#pragma unroll
    for (int c = 0; c < 7; ++c) {
        float rc = __shfl(r_own, gbase + c);
        o0 += We[c * 64 + f0 + 0] * rc;
        o1 += We[c * 64 + f0 + 1] * rc;
        o2 += We[c * 64 + f0 + 2] * rc;
        o3 += We[c * 64 + f0 + 3] * rc;
    }
    ushort4 skv = *reinterpret_cast<const ushort4*>(&skbb[(size_t)n * 64 + f0]);
    float4 res;
    res.x = o0 * inv + bf16_f(skv.x);
    res.y = o1 * inv + bf16_f(skv.y);
    res.z = o2 * inv + bf16_f(skv.z);
    res.w = o3 * inv + bf16_f(skv.w);
    if (act) {
        res.x = res.x > 0.f ? res.x : (__expf(res.x) - 1.f);
        res.y = res.y > 0.f ? res.y : (__expf(res.y) - 1.f);
        res.z = res.z > 0.f ? res.z : (__expf(res.z) - 1.f);
        res.w = res.w > 0.f ? res.w : (__expf(res.w) - 1.f);
    }
    ushort4 hb4;
    hb4.x = rne_bf16(res.x); hb4.y = rne_bf16(res.y); hb4.z = rne_bf16(res.z); hb4.w = rne_bf16(res.w);
    *reinterpret_cast<ushort4*>(&hb[(size_t)n * 64 + f0]) = hb4;
    if (initmax) {
        *reinterpret_cast<ushort4*>(&hmaxb[(size_t)n * 64 + f0]) = hb4;
    } else {
        ushort4 hm4 = *reinterpret_cast<const ushort4*>(&hmaxb[(size_t)n * 64 + f0]);
        hm4.x = rne_bf16(fmaxf(bf16_f(hm4.x), res.x));
        hm4.y = rne_bf16(fmaxf(bf16_f(hm4.y), res.y));
        hm4.z = rne_bf16(fmaxf(bf16_f(hm4.z), res.z));
        hm4.w = rne_bf16(fmaxf(bf16_f(hm4.w), res.w));
        *reinterpret_cast<ushort4*>(&hmaxb[(size_t)n * 64 + f0]) = hm4;
    }
}

// ---------------- gate MLP per node (bf16 hmax input, no atomics) ----------------
__global__ __launch_bounds__(256) void gate_kernel(const u16* __restrict__ h, fp g1W, fp g1b, fp g2W,
                                                   fp g2b, float* __restrict__ gate) {
    __shared__ float hs[4][64];
    int w = threadIdx.x >> 6, lane = threadIdx.x & 63;
    int n = blockIdx.x * 4 + w;
    hs[w][lane] = bf16_f(h[(size_t)n * 64 + lane]);
    __syncthreads();
    float a = 0.f;
    for (int f = 0; f < 64; ++f) a += hs[w][f] * g1W[f * 64 + lane];
    a = fmaxf(a + g1b[lane], 0.f);
    float val = a * g2W[lane];
#pragma unroll
    for (int off = 32; off; off >>= 1) val += __shfl_xor(val, off);
    if (lane == 0) gate[n] = val + g2b[0];
}

// per-graph max via wave-segmented atomicMax (~1600 atomics total)
__global__ __launch_bounds__(256) void gmax_kernel(const float* __restrict__ gate,
                                                   const int* __restrict__ batch,
                                                   u32* __restrict__ gmaxEnc) {
    int i = blockIdx.x * 256 + threadIdx.x;
    if (i >= N_NODES) return;
    int lane = threadIdx.x & 63;
    int g = batch[i];
    u32 e = f_enc(gate[i]);
    int waveBase = i - lane;
    if (waveBase + 63 < N_NODES) {
        int g0 = __shfl(g, 0), g63 = __shfl(g, 63);
        if (g0 == g63) {
            u32 t = e;
#pragma unroll
            for (int off = 32; off; off >>= 1) t = max(t, (u32)__shfl_xor((int)t, off));
            if (lane == 0) atomicMax(&gmaxEnc[g], t);
            return;
        }
    }
    atomicMax(&gmaxEnc[g], e);
}

// fused exp + per-graph sum + weighted accumulation (bf16 h)
#define PCHUNK 256
__global__ __launch_bounds__(256) void pool_accum_kernel(const u16* __restrict__ h,
                                                         const float* __restrict__ gate,
                                                         const int* __restrict__ batch,
                                                         const u32* __restrict__ gmaxEnc,
                                                         float* __restrict__ pooled,
                                                         float* __restrict__ gsum) {
    int w = threadIdx.x >> 6, lane = threadIdx.x & 63;
    int base = blockIdx.x * PCHUNK;
    float acc = 0.f, gacc = 0.f;
    int cur = -1;
    for (int t = 0; t < PCHUNK / 4; ++t) {
        int i = base + w + 4 * t;
        if (i >= N_NODES) break;
        int g = batch[i];
        if (g != cur) {
            if (cur >= 0) {
                atomicAdd(&pooled[cur * 64 + lane], acc);
                if (lane == 0) atomicAdd(&gsum[cur], gacc);
            }
            acc = 0.f;
            gacc = 0.f;
            cur = g;
        }
        float p = __expf(gate[i] - f_dec(gmaxEnc[g]));
        gacc += p;
        acc += p * bf16_f(h[(size_t)i * 64 + lane]);
    }
    if (cur >= 0) {
        atomicAdd(&pooled[cur * 64 + lane], acc);
        if (lane == 0) atomicAdd(&gsum[cur], gacc);
    }
}

// ---------------- 6-expert MLP head (f32 output); divides pooled by gsum ----------------
__global__ __launch_bounds__(256) void mlp_kernel(const float* __restrict__ pooled,
                                                  const float* __restrict__ gsum, fp m0W, fp m0b, fp m1W,
                                                  fp m1b, fp m2W, fp m2b, fp m3W, fp m3b,
                                                  float* __restrict__ out) {
    int e = blockIdx.x, tid = threadIdx.x;
    __shared__ float P[64 * 64];
    __shared__ float A1[64 * 32];
    __shared__ float A2[64 * 16];
    __shared__ float A3[64 * 8];
    for (int i = tid; i < 64 * 64; i += 256) P[i] = pooled[i] / (gsum[i >> 6] + 1e-16f);
    __syncthreads();
    fp W0 = m0W + e * 64 * 32; fp B0 = m0b + e * 32;
    for (int i = tid; i < 64 * 32; i += 256) {
        int g = i >> 5, c = i & 31;
        float a = B0[c];
        for (int f = 0; f < 64; ++f) a += P[g * 64 + f] * W0[f * 32 + c];
        A1[i] = a > 0.f ? a : (__expf(a) - 1.f);
    }
    __syncthreads();
    fp W1 = m1W + e * 32 * 16; fp B1 = m1b + e * 16;
    for (int i = tid; i < 64 * 16; i += 256) {
        int g = i >> 4, c = i & 15;
        float a = B1[c];
        for (int f = 0; f < 32; ++f) a += A1[g * 32 + f] * W1[f * 16 + c];
        A2[i] = a > 0.f ? a : (__expf(a) - 1.f);
    }
    __syncthreads();
    fp W2 = m2W + e * 16 * 8; fp B2 = m2b + e * 8;
    for (int i = tid; i < 64 * 8; i += 256) {
        int g = i >> 3, c = i & 7;
        float a = B2[c];
        for (int f = 0; f < 16; ++f) a += A2[g * 16 + f] * W2[f * 8 + c];
        A3[i] = a > 0.f ? a : (__expf(a) - 1.f);
    }
    __syncthreads();
    fp W3 = m3W + e * 8;
    if (tid < 64) {
        int g = tid;
        float a = m3b[e];
        for (int j = 0; j < 8; ++j) a += A3[g * 8 + j] * W3[j];
        out[g * 6 + e] = a;
    }
}

__global__ __launch_bounds__(64) void loss_kernel(const float* __restrict__ preds, fp y,
                                                  float* __restrict__ out) {
    int lane = threadIdx.x;
    float lsum = 0.f;
    if (lane < 6) {
        float acc = 0.f;
        for (int g = 0; g < 64; ++g) {
            float d = preds[g * 6 + lane] - y[g * 6 + lane];
            acc += d * d;
        }
        lsum = sqrtf(acc / 64.f);
    }
#pragma unroll
    for (int off = 32; off; off >>= 1) lsum += __shfl_xor(lsum, off);
    if (lane == 0) out[384] = lsum;
}

extern "C" void kernel_launch(void* const* d_in, const int* in_sizes, int n_in, void* d_out, int out_size,
                              void* d_ws, size_t ws_size, hipStream_t stream) {
    bool dictOrder = (in_sizes[1] == 2 * N_EDGES);
    int iEI = dictOrder ? 1 : 33;
    int iEA = dictOrder ? 2 : 1;
    int iBT = dictOrder ? 3 : 34;
    int iY  = dictOrder ? 4 : 2;
    int w0  = dictOrder ? 5 : 3;

    fp x = (fp)d_in[0];
    const int* ei = (const int*)d_in[iEI];
    fp eattr = (fp)d_in[iEA];
    const int* batch = (const int*)d_in[iBT];
    fp y = (fp)d_in[iY];
    fp Wq0 = (fp)d_in[w0 + 0], bq0 = (fp)d_in[w0 + 1], Wk0 = (fp)d_in[w0 + 2], bk0 = (fp)d_in[w0 + 3];
    fp Wv0 = (fp)d_in[w0 + 4], bv0 = (fp)d_in[w0 + 5], We0 = (fp)d_in[w0 + 6];
    fp Ws0 = (fp)d_in[w0 + 7], bs0 = (fp)d_in[w0 + 8];
    fp Wq = (fp)d_in[w0 + 9], bq = (fp)d_in[w0 + 10], Wk = (fp)d_in[w0 + 11], bk = (fp)d_in[w0 + 12];
    fp Wv = (fp)d_in[w0 + 13], bv = (fp)d_in[w0 + 14], Wel = (fp)d_in[w0 + 15];
    fp Ws = (fp)d_in[w0 + 16], bs = (fp)d_in[w0 + 17];
    fp g1W = (fp)d_in[w0 + 18], g1b = (fp)d_in[w0 + 19], g2W = (fp)d_in[w0 + 20], g2b = (fp)d_in[w0 + 21];
    fp m0W = (fp)d_in[w0 + 22], m0b = (fp)d_in[w0 + 23], m1W = (fp)d_in[w0 + 24], m1b = (fp)d_in[w0 + 25];
    fp m2W = (fp)d_in[w0 + 26], m2b = (fp)d_in[w0 + 27], m3W = (fp)d_in[w0 + 28], m3b = (fp)d_in[w0 + 29];

    const int* srcArr = ei;
    const int* dstArr = ei + N_EDGES;

    char* wsp = (char*)d_ws;
    auto alloc = [&](size_t bytes) -> void* {
        void* p = (void*)wsp;
        wsp += (bytes + 255) & ~(size_t)255;
        return p;
    };
    u16* qb = (u16*)alloc((size_t)N_NODES * 64 * 2);         // bf16, prescaled 1/8
    u32* kvp = (u32*)alloc((size_t)N_NODES * 64 * 4);        // packed bf16 k|v<<16 per feature
    u16* skbb = (u16*)alloc((size_t)N_NODES * 64 * 2);       // bf16 skip
    u16* hb = (u16*)alloc((size_t)N_NODES * 64 * 2);         // h bf16 (gemm A for layers 1-3)
    u16* xb = (u16*)alloc((size_t)N_NODES * IN_CH * 2);      // x bf16
    u16* hmaxb = (u16*)alloc((size_t)N_NODES * 64 * 2);      // JK max, bf16
    float* gate = (float*)alloc((size_t)N_NODES * 4);
    float* pooled = (float*)alloc(64 * 64 * 4);
    u32* gmaxEnc = (u32*)alloc(N_GRAPHS * 4);
    float* gsum = (float*)alloc(N_GRAPHS * 4);
    int* row_ptr = (int*)alloc((N_NODES + 1) * 4);
    int* cursor = (int*)alloc((size_t)N_NODES * 4);
    int* csr_src = (int*)alloc((size_t)N_EDGES * 4);
    uint4* eab = (uint4*)alloc((size_t)N_EDGES * 16);
    u16* Bp0 = (u16*)alloc((size_t)(IN_CH / 32) * 16 * 512 * 2);
    u16* Bp1 = (u16*)alloc((size_t)(DIM / 32) * 16 * 512 * 2);
    u16* Bp2 = (u16*)alloc((size_t)(DIM / 32) * 16 * 512 * 2);
    u16* Bp3 = (u16*)alloc((size_t)(DIM / 32) * 16 * 512 * 2);
    int* blksum = (int*)alloc(256 * 4);
    (void)ws_size;
    (void)n_in;

    float* outF = (float*)d_out;  // [0..383] preds, [384] total_loss

    // ---- CSR build (by dst) + weight/x conversion ----
    hipMemsetAsync(cursor, 0, (size_t)N_NODES * 4, stream);
    hipMemsetAsync(gmaxEnc, 0, N_GRAPHS * 4, stream);
    hipMemsetAsync(gsum, 0, N_GRAPHS * 4, stream);
    hipMemsetAsync(pooled, 0, 64 * 64 * 4, stream);
    count_kernel<<<(N_EDGES + 255) / 256, 256, 0, stream>>>(dstArr, cursor);
    scan1_kernel<<<NBLK, 512, 0, stream>>>(cursor, row_ptr, blksum);
    scan2_kernel<<<1, 256, 0, stream>>>(blksum);
    scan3_kernel<<<NBLK, 512, 0, stream>>>(row_ptr, blksum, cursor);
    for (int p = 0; p < NPASS; ++p)
        scatter_pass_kernel<<<(N_EDGES + 255) / 256, 256, 0, stream>>>(
            srcArr, dstArr, eattr, cursor, csr_src, eab, p * PASS_SZ, (p + 1) * PASS_SZ);
    cvt_bf16_kernel<<<(N_NODES * IN_CH / 4 + 255) / 256, 256, 0, stream>>>(x, xb, N_NODES * IN_CH / 4);
    packW_kernel<<<((IN_CH / 32) * 16 * 512 + 255) / 256, 256, 0, stream>>>(Wq0, Wk0, Wv0, Ws0, Bp0, IN_CH);
    u16* Bps[3] = {Bp1, Bp2, Bp3};
    for (int i = 0; i < N_CONVS; ++i)
        packW_kernel<<<((DIM / 32) * 16 * 512 + 255) / 256, 256, 0, stream>>>(
            Wq + i * 4096, Wk + i * 4096, Wv + i * 4096, Ws + i * 4096, Bps[i], DIM);

    int nodeGrid = N_NODES / 16;  // 4 nodes per wave, 4 waves per block
    // layer 0 (conv_first, 128 -> 64), ELU, init hmax
    gemm_mfma_kernel<IN_CH><<<N_NODES / 32, 256, 0, stream>>>(xb, Bp0, bq0, bk0, bv0, bs0, qb, kvp, skbb);
    node_kernel<<<nodeGrid, 256, 0, stream>>>(qb, kvp, skbb, eab, We0, row_ptr, csr_src, hb, hmaxb, 1, 1);
    // layers 1..3 (64 -> 64); ELU except last; JK running max
    for (int i = 0; i < N_CONVS; ++i) {
        gemm_mfma_kernel<DIM><<<N_NODES / 32, 256, 0, stream>>>(hb, Bps[i], bq + i * 64, bk + i * 64,
                                                                bv + i * 64, bs + i * 64, qb, kvp, skbb);
        node_kernel<<<nodeGrid, 256, 0, stream>>>(qb, kvp, skbb, eab, Wel + i * 448, row_ptr,
                                                  csr_src, hb, hmaxb, (i < N_CONVS - 1) ? 1 : 0, 0);
    }
    // pooling head: gate -> segmented max -> fused exp/sum/accum -> MLP (divides by gsum)
    gate_kernel<<<N_NODES / 4, 256, 0, stream>>>(hmaxb, g1W, g1b, g2W, g2b, gate);
    gmax_kernel<<<(N_NODES + 255) / 256, 256, 0, stream>>>(gate, batch, gmaxEnc);
    pool_accum_kernel<<<(N_NODES + PCHUNK - 1) / PCHUNK, 256, 0, stream>>>(hmaxb, gate, batch, gmaxEnc,
                                                                           pooled, gsum);
    mlp_kernel<<<6, 256, 0, stream>>>(pooled, gsum, m0W, m0b, m1W, m1b, m2W, m2b, m3W, m3b, outF);
    loss_kernel<<<1, 64, 0, stream>>>(outF, y, outF);
}

// Round 21
// 754.237 us; speedup vs baseline: 1.1596x; 1.0125x over previous
//
#include <hip/hip_runtime.h>
#include <math.h>

#define N_NODES 100000
#define N_EDGES 1600000
#define N_GRAPHS 64
#define IN_CH 128
#define DIM 64
#define N_CONVS 3
#define NBLK 196      // ceil(100000/512)
#define NPASS 8
#define PASS_SZ 12500  // N_NODES / NPASS

typedef const float* fp;
typedef unsigned int u32;
typedef unsigned short u16;
typedef __attribute__((ext_vector_type(8))) short short8v;
typedef __attribute__((ext_vector_type(4))) float f32x4;

__device__ inline u16 rne_bf16(float f) {
    u32 u = __float_as_uint(f);
    return (u16)((u + 0x7fffu + ((u >> 16) & 1u)) >> 16);
}
__device__ inline float bf16_f(u16 w) { return __uint_as_float((u32)w << 16); }
__device__ inline float bf16lo_f(u32 w) { return __uint_as_float(w << 16); }
__device__ inline float bf16hi_f(u32 w) { return __uint_as_float(w & 0xffff0000u); }
// order-preserving float <-> uint encoding (for atomicMax on floats incl. negatives)
__device__ inline u32 f_enc(float f) {
    u32 u = __float_as_uint(f);
    return (u & 0x80000000u) ? ~u : (u | 0x80000000u);
}
__device__ inline float f_dec(u32 e) {
    u32 u = (e & 0x80000000u) ? (e & 0x7fffffffu) : ~e;
    return __uint_as_float(u);
}

// ---------------- CSR build ----------------
__global__ __launch_bounds__(256) void count_kernel(const int* __restrict__ dst, int* __restrict__ cnt) {
    int j = blockIdx.x * 256 + threadIdx.x;
    if (j < N_EDGES) {
        int d = dst[j];
        if ((unsigned)d < N_NODES) atomicAdd(&cnt[d], 1);
    }
}

__global__ __launch_bounds__(512) void scan1_kernel(const int* __restrict__ cnt, int* __restrict__ rp,
                                                    int* __restrict__ blksum) {
    __shared__ int tmp[512];
    int t = threadIdx.x, i = blockIdx.x * 512 + t;
    int v0 = (i < N_NODES) ? cnt[i] : 0;
    tmp[t] = v0;
    __syncthreads();
    for (int off = 1; off < 512; off <<= 1) {
        int add = (t >= off) ? tmp[t - off] : 0;
        __syncthreads();
        tmp[t] += add;
        __syncthreads();
    }
    if (i < N_NODES) rp[i] = tmp[t] - v0;
    if (t == 511) blksum[blockIdx.x] = tmp[511];
}

__global__ __launch_bounds__(256) void scan2_kernel(int* __restrict__ blksum) {
    __shared__ int tmp[256];
    int t = threadIdx.x;
    int v0 = (t < NBLK) ? blksum[t] : 0;
    tmp[t] = v0;
    __syncthreads();
    for (int off = 1; off < 256; off <<= 1) {
        int add = (t >= off) ? tmp[t - off] : 0;
        __syncthreads();
        tmp[t] += add;
        __syncthreads();
    }
    if (t < NBLK) blksum[t] = tmp[t] - v0;
}

__global__ __launch_bounds__(512) void scan3_kernel(int* __restrict__ rp, const int* __restrict__ blksum,
                                                    int* __restrict__ cursor) {
    int t = threadIdx.x, i = blockIdx.x * 512 + t;
    if (i < N_NODES) {
        int v = rp[i] + blksum[blockIdx.x];
        rp[i] = v;
        cursor[i] = v;
    }
    if (i == 0) rp[N_NODES] = N_EDGES;
}

// range-split scatter with inline ea->bf16 pack: only edges with dst in [lo, hi)
__global__ __launch_bounds__(256) void scatter_pass_kernel(const int* __restrict__ src,
                                                           const int* __restrict__ dst, fp ea,
                                                           int* __restrict__ cursor,
                                                           int* __restrict__ csr_src,
                                                           uint4* __restrict__ eab, int lo, int hi) {
    int j = blockIdx.x * 256 + threadIdx.x;
    if (j < N_EDGES) {
        int d = dst[j];
        if (d < lo || d >= hi || (unsigned)d >= N_NODES) return;
        int pos = atomicAdd(&cursor[d], 1);
        if ((unsigned)pos < N_EDGES) {
            int s = src[j];
            csr_src[pos] = ((unsigned)s < N_NODES) ? s : 0;
            size_t sb = (size_t)j * 7;
            u16 b[8];
#pragma unroll
            for (int c = 0; c < 7; ++c) b[c] = rne_bf16(ea[sb + c]);
            b[7] = 0;
            uint4 o;
            o.x = b[0] | ((u32)b[1] << 16);
            o.y = b[2] | ((u32)b[3] << 16);
            o.z = b[4] | ((u32)b[5] << 16);
            o.w = b[6] | ((u32)b[7] << 16);
            eab[pos] = o;
        }
    }
}

// ---------------- x -> bf16 ----------------
__global__ __launch_bounds__(256) void cvt_bf16_kernel(const float* __restrict__ in, u16* __restrict__ out,
                                                       int n4) {
    int i = blockIdx.x * 256 + threadIdx.x;
    if (i < n4) {
        float4 v = reinterpret_cast<const float4*>(in)[i];
        ushort4 o;
        o.x = rne_bf16(v.x); o.y = rne_bf16(v.y); o.z = rne_bf16(v.z); o.w = rne_bf16(v.w);
        reinterpret_cast<ushort4*>(out)[i] = o;
    }
}

// ---------------- pack W (q|k|v|s -> K x 256) into MFMA B-fragment order ----------------
__global__ __launch_bounds__(256) void packW_kernel(fp Wq, fp Wk, fp Wv, fp Ws, u16* __restrict__ Bp,
                                                    int K) {
    int total = (K / 32) * 16 * 512;
    int tid = blockIdx.x * 256 + threadIdx.x;
    if (tid >= total) return;
    int j = tid & 7, l = (tid >> 3) & 63, fragid = tid >> 9;
    int tk = fragid >> 4, gtn = fragid & 15;
    int k = tk * 32 + ((l >> 4) << 3) + j;
    int n = (gtn << 4) + (l & 15);
    int mat = n >> 6, cn = n & 63;
    fp W = mat == 0 ? Wq : mat == 1 ? Wk : mat == 2 ? Wv : Ws;
    Bp[tid] = rne_bf16(W[k * 64 + cn]);
}

// ---------------- fused MFMA GEMM: q(bf16, *1/8) | kv(dense u32 via LDS pack) | skip(bf16) ----------------
template <int K>
__global__ __launch_bounds__(256) void gemm_mfma_kernel(
    const u16* __restrict__ A, const u16* __restrict__ Bp,
    fp bq, fp bk, fp bv, fp bs,
    u16* __restrict__ qb, u32* __restrict__ kvp, u16* __restrict__ skbb) {
    constexpr int NTK = K / 32;
    __shared__ u16 kls[32][64];
    int wave = threadIdx.x >> 6;  // 0:q 1:k 2:v 3:skip
    int l = threadIdx.x & 63;
    int lr = l & 15, lg = l >> 4;
    int row0 = blockIdx.x * 32;
    short8v a[2][NTK];
#pragma unroll
    for (int mi = 0; mi < 2; ++mi)
#pragma unroll
        for (int tk = 0; tk < NTK; ++tk)
            a[mi][tk] = *reinterpret_cast<const short8v*>(
                &A[(size_t)(row0 + mi * 16 + lr) * K + tk * 32 + lg * 8]);
    f32x4 c[2][4] = {};
#pragma unroll
    for (int tn = 0; tn < 4; ++tn) {
        int gtn = wave * 4 + tn;
#pragma unroll
        for (int tk = 0; tk < NTK; ++tk) {
            short8v b = *reinterpret_cast<const short8v*>(&Bp[((size_t)(tk * 16 + gtn) * 64 + l) * 8]);
            c[0][tn] = __builtin_amdgcn_mfma_f32_16x16x32_bf16(a[0][tk], b, c[0][tn], 0, 0, 0);
            c[1][tn] = __builtin_amdgcn_mfma_f32_16x16x32_bf16(a[1][tk], b, c[1][tn], 0, 0, 0);
        }
    }
    fp bias = wave == 0 ? bq : wave == 1 ? bk : wave == 2 ? bv : bs;
    if (wave == 1) {  // stage k into LDS
#pragma unroll
        for (int tn = 0; tn < 4; ++tn) {
            int cl = tn * 16 + lr;
            float bb = bias[cl];
#pragma unroll
            for (int mi = 0; mi < 2; ++mi)
#pragma unroll
                for (int r = 0; r < 4; ++r) {
                    int rr = mi * 16 + lg * 4 + r;
                    kls[rr][cl] = rne_bf16(c[mi][tn][r] + bb);
                }
        }
    }
    __syncthreads();
    if (wave == 1) return;
#pragma unroll
    for (int tn = 0; tn < 4; ++tn) {
        int cl = tn * 16 + lr;
        float bb = bias[cl];
#pragma unroll
        for (int mi = 0; mi < 2; ++mi)
#pragma unroll
            for (int r = 0; r < 4; ++r) {
                int rr = mi * 16 + lg * 4 + r;
                size_t row = row0 + rr;
                float val = c[mi][tn][r] + bb;
                if (wave == 0) qb[row * 64 + cl] = rne_bf16(val * 0.125f);
                else if (wave == 3) skbb[row * 64 + cl] = rne_bf16(val);
                else kvp[row * 64 + cl] = (u32)kls[rr][cl] | ((u32)rne_bf16(val) << 16);
            }
    }
}

// ---------------- per-node edge aggregation: 4 nodes/wave, 16 lanes/node, e-channel-per-lane ----------------
__global__ __launch_bounds__(256) void node_kernel(
    const u16* __restrict__ qb, const u32* __restrict__ kvp,
    const u16* __restrict__ skbb, const uint4* __restrict__ eab, fp We,
    const int* __restrict__ row_ptr, const int* __restrict__ csr_src,
    u16* __restrict__ hb, u16* __restrict__ hmaxb, int act, int initmax) {
    int tid = threadIdx.x;
    int lane = tid & 63;
    int g = lane >> 4, fl = lane & 15;
    int gbase = g << 4;
    int n = blockIdx.x * 16 + (tid >> 6) * 4 + g;
    int f0 = fl * 4;
    ushort4 qv = *reinterpret_cast<const ushort4*>(&qb[(size_t)n * 64 + f0]);
    float4 q4;
    q4.x = bf16_f(qv.x); q4.y = bf16_f(qv.y); q4.z = bf16_f(qv.z); q4.w = bf16_f(qv.w);
    // qw_own: lane fl (fl<7) keeps qw[fl] = sum_f q[f]*We[fl][f]; other lanes 0
    float qw_own = 0.f;
#pragma unroll
    for (int c = 0; c < 7; ++c) {
        float4 w4 = *reinterpret_cast<const float4*>(&We[c * 64 + f0]);
        float t = q4.x * w4.x + q4.y * w4.y + q4.z * w4.z + q4.w * w4.w;
        t += __shfl_xor(t, 1);
        t += __shfl_xor(t, 2);
        t += __shfl_xor(t, 4);
        t += __shfl_xor(t, 8);
        if (fl == c) qw_own = t;
    }
    int beg = row_ptr[n], end = row_ptr[n + 1];
    float s = 0.f;
    float ax = 0.f, ay = 0.f, az = 0.f, aw = 0.f;
    float r_own = 0.f;  // sum pe * ea[fl]  (lane's channel)

    for (int p = beg; p < end; p += 4) {
        int svi = p + (fl & 3);
        svi = svi < end ? svi : end - 1;
        int sv = csr_src[svi];
#pragma unroll
        for (int j = 0; j < 4; ++j) {
            int pj = p + j;
            int pc = pj < end ? pj : end - 1;
            int sn = __shfl(sv, gbase + j);
            uint4 kv4 = *reinterpret_cast<const uint4*>(&kvp[(size_t)sn * 64 + f0]);
            uint4 e4 = eab[pc];
            // lane's edge-attr channel (fl<7 valid; fl==7 -> packed 0; fl>=8 garbage but unused)
            u32 w01 = (fl & 2) ? e4.y : e4.x;
            u32 w23 = (fl & 2) ? e4.w : e4.z;
            u32 wsel = (fl & 4) ? w23 : w01;
            float e_own = (fl & 1) ? bf16hi_f(wsel) : bf16lo_f(wsel);
            float kf0 = bf16lo_f(kv4.x), vf0 = bf16hi_f(kv4.x);
            float kf1 = bf16lo_f(kv4.y), vf1 = bf16hi_f(kv4.y);
            float kf2 = bf16lo_f(kv4.z), vf2 = bf16hi_f(kv4.z);
            float kf3 = bf16lo_f(kv4.w), vf3 = bf16hi_f(kv4.w);
            // fused alpha: butterfly over (q.k partials + qw[fl]*ea[fl])
            float d = q4.x * kf0 + q4.y * kf1 + q4.z * kf2 + q4.w * kf3 + qw_own * e_own;
            d += __shfl_xor(d, 1);
            d += __shfl_xor(d, 2);
            d += __shfl_xor(d, 4);
            d += __shfl_xor(d, 8);
            float pe = (pj < end) ? __expf(d) : 0.f;
            s += pe;
            ax += pe * vf0; ay += pe * vf1; az += pe * vf2; aw += pe * vf3;
            r_own += pe * e_own;
        }
    }
    float inv = 1.f / (s + 1e-16f);
    float o0 = ax, o1 = ay, o2 = az, o3 = aw;
#pragma unroll
    for (int c = 0; c < 7; ++c) {
        float rc = __shfl(r_own, gbase + c);
        o0 += We[c * 64 + f0 + 0] * rc;
        o1 += We[c * 64 + f0 + 1] * rc;
        o2 += We[c * 64 + f0 + 2] * rc;
        o3 += We[c * 64 + f0 + 3] * rc;
    }
    ushort4 skv = *reinterpret_cast<const ushort4*>(&skbb[(size_t)n * 64 + f0]);
    float4 res;
    res.x = o0 * inv + bf16_f(skv.x);
    res.y = o1 * inv + bf16_f(skv.y);
    res.z = o2 * inv + bf16_f(skv.z);
    res.w = o3 * inv + bf16_f(skv.w);
    if (act) {
        res.x = res.x > 0.f ? res.x : (__expf(res.x) - 1.f);
        res.y = res.y > 0.f ? res.y : (__expf(res.y) - 1.f);
        res.z = res.z > 0.f ? res.z : (__expf(res.z) - 1.f);
        res.w = res.w > 0.f ? res.w : (__expf(res.w) - 1.f);
    }
    ushort4 hb4;
    hb4.x = rne_bf16(res.x); hb4.y = rne_bf16(res.y); hb4.z = rne_bf16(res.z); hb4.w = rne_bf16(res.w);
    *reinterpret_cast<ushort4*>(&hb[(size_t)n * 64 + f0]) = hb4;
    if (initmax) {
        *reinterpret_cast<ushort4*>(&hmaxb[(size_t)n * 64 + f0]) = hb4;
    } else {
        ushort4 hm4 = *reinterpret_cast<const ushort4*>(&hmaxb[(size_t)n * 64 + f0]);
        hm4.x = rne_bf16(fmaxf(bf16_f(hm4.x), res.x));
        hm4.y = rne_bf16(fmaxf(bf16_f(hm4.y), res.y));
        hm4.z = rne_bf16(fmaxf(bf16_f(hm4.z), res.z));
        hm4.w = rne_bf16(fmaxf(bf16_f(hm4.w), res.w));
        *reinterpret_cast<ushort4*>(&hmaxb[(size_t)n * 64 + f0]) = hm4;
    }
}

// ---------------- gate MLP per node (bf16 hmax input, no atomics) ----------------
__global__ __launch_bounds__(256) void gate_kernel(const u16* __restrict__ h, fp g1W, fp g1b, fp g2W,
                                                   fp g2b, float* __restrict__ gate) {
    __shared__ float hs[4][64];
    int w = threadIdx.x >> 6, lane = threadIdx.x & 63;
    int n = blockIdx.x * 4 + w;
    hs[w][lane] = bf16_f(h[(size_t)n * 64 + lane]);
    __syncthreads();
    float a = 0.f;
    for (int f = 0; f < 64; ++f) a += hs[w][f] * g1W[f * 64 + lane];
    a = fmaxf(a + g1b[lane], 0.f);
    float val = a * g2W[lane];
#pragma unroll
    for (int off = 32; off; off >>= 1) val += __shfl_xor(val, off);
    if (lane == 0) gate[n] = val + g2b[0];
}

// per-graph max via wave-segmented atomicMax (~1600 atomics total)
__global__ __launch_bounds__(256) void gmax_kernel(const float* __restrict__ gate,
                                                   const int* __restrict__ batch,
                                                   u32* __restrict__ gmaxEnc) {
    int i = blockIdx.x * 256 + threadIdx.x;
    if (i >= N_NODES) return;
    int lane = threadIdx.x & 63;
    int g = batch[i];
    u32 e = f_enc(gate[i]);
    int waveBase = i - lane;
    if (waveBase + 63 < N_NODES) {
        int g0 = __shfl(g, 0), g63 = __shfl(g, 63);
        if (g0 == g63) {
            u32 t = e;
#pragma unroll
            for (int off = 32; off; off >>= 1) t = max(t, (u32)__shfl_xor((int)t, off));
            if (lane == 0) atomicMax(&gmaxEnc[g], t);
            return;
        }
    }
    atomicMax(&gmaxEnc[g], e);
}

// fused exp + per-graph sum + weighted accumulation (bf16 h)
#define PCHUNK 256
__global__ __launch_bounds__(256) void pool_accum_kernel(const u16* __restrict__ h,
                                                         const float* __restrict__ gate,
                                                         const int* __restrict__ batch,
                                                         const u32* __restrict__ gmaxEnc,
                                                         float* __restrict__ pooled,
                                                         float* __restrict__ gsum) {
    int w = threadIdx.x >> 6, lane = threadIdx.x & 63;
    int base = blockIdx.x * PCHUNK;
    float acc = 0.f, gacc = 0.f;
    int cur = -1;
    for (int t = 0; t < PCHUNK / 4; ++t) {
        int i = base + w + 4 * t;
        if (i >= N_NODES) break;
        int g = batch[i];
        if (g != cur) {
            if (cur >= 0) {
                atomicAdd(&pooled[cur * 64 + lane], acc);
                if (lane == 0) atomicAdd(&gsum[cur], gacc);
            }
            acc = 0.f;
            gacc = 0.f;
            cur = g;
        }
        float p = __expf(gate[i] - f_dec(gmaxEnc[g]));
        gacc += p;
        acc += p * bf16_f(h[(size_t)i * 64 + lane]);
    }
    if (cur >= 0) {
        atomicAdd(&pooled[cur * 64 + lane], acc);
        if (lane == 0) atomicAdd(&gsum[cur], gacc);
    }
}

// ---------------- 6-expert MLP head (f32 output); divides pooled by gsum ----------------
__global__ __launch_bounds__(256) void mlp_kernel(const float* __restrict__ pooled,
                                                  const float* __restrict__ gsum, fp m0W, fp m0b, fp m1W,
                                                  fp m1b, fp m2W, fp m2b, fp m3W, fp m3b,
                                                  float* __restrict__ out) {
    int e = blockIdx.x, tid = threadIdx.x;
    __shared__ float P[64 * 64];
    __shared__ float A1[64 * 32];
    __shared__ float A2[64 * 16];
    __shared__ float A3[64 * 8];
    for (int i = tid; i < 64 * 64; i += 256) P[i] = pooled[i] / (gsum[i >> 6] + 1e-16f);
    __syncthreads();
    fp W0 = m0W + e * 64 * 32; fp B0 = m0b + e * 32;
    for (int i = tid; i < 64 * 32; i += 256) {
        int g = i >> 5, c = i & 31;
        float a = B0[c];
        for (int f = 0; f < 64; ++f) a += P[g * 64 + f] * W0[f * 32 + c];
        A1[i] = a > 0.f ? a : (__expf(a) - 1.f);
    }
    __syncthreads();
    fp W1 = m1W + e * 32 * 16; fp B1 = m1b + e * 16;
    for (int i = tid; i < 64 * 16; i += 256) {
        int g = i >> 4, c = i & 15;
        float a = B1[c];
        for (int f = 0; f < 32; ++f) a += A1[g * 32 + f] * W1[f * 16 + c];
        A2[i] = a > 0.f ? a : (__expf(a) - 1.f);
    }
    __syncthreads();
    fp W2 = m2W + e * 16 * 8; fp B2 = m2b + e * 8;
    for (int i = tid; i < 64 * 8; i += 256) {
        int g = i >> 3, c = i & 7;
        float a = B2[c];
        for (int f = 0; f < 16; ++f) a += A2[g * 16 + f] * W2[f * 8 + c];
        A3[i] = a > 0.f ? a : (__expf(a) - 1.f);
    }
    __syncthreads();
    fp W3 = m3W + e * 8;
    if (tid < 64) {
        int g = tid;
        float a = m3b[e];
        for (int j = 0; j < 8; ++j) a += A3[g * 8 + j] * W3[j];
        out[g * 6 + e] = a;
    }
}

__global__ __launch_bounds__(64) void loss_kernel(const float* __restrict__ preds, fp y,
                                                  float* __restrict__ out) {
    int lane = threadIdx.x;
    float lsum = 0.f;
    if (lane < 6) {
        float acc = 0.f;
        for (int g = 0; g < 64; ++g) {
            float d = preds[g * 6 + lane] - y[g * 6 + lane];
            acc += d * d;
        }
        lsum = sqrtf(acc / 64.f);
    }
#pragma unroll
    for (int off = 32; off; off >>= 1) lsum += __shfl_xor(lsum, off);
    if (lane == 0) out[384] = lsum;
}

extern "C" void kernel_launch(void* const* d_in, const int* in_sizes, int n_in, void* d_out, int out_size,
                              void* d_ws, size_t ws_size, hipStream_t stream) {
    bool dictOrder = (in_sizes[1] == 2 * N_EDGES);
    int iEI = dictOrder ? 1 : 33;
    int iEA = dictOrder ? 2 : 1;
    int iBT = dictOrder ? 3 : 34;
    int iY  = dictOrder ? 4 : 2;
    int w0  = dictOrder ? 5 : 3;

    fp x = (fp)d_in[0];
    const int* ei = (const int*)d_in[iEI];
    fp eattr = (fp)d_in[iEA];
    const int* batch = (const int*)d_in[iBT];
    fp y = (fp)d_in[iY];
    fp Wq0 = (fp)d_in[w0 + 0], bq0 = (fp)d_in[w0 + 1], Wk0 = (fp)d_in[w0 + 2], bk0 = (fp)d_in[w0 + 3];
    fp Wv0 = (fp)d_in[w0 + 4], bv0 = (fp)d_in[w0 + 5], We0 = (fp)d_in[w0 + 6];
    fp Ws0 = (fp)d_in[w0 + 7], bs0 = (fp)d_in[w0 + 8];
    fp Wq = (fp)d_in[w0 + 9], bq = (fp)d_in[w0 + 10], Wk = (fp)d_in[w0 + 11], bk = (fp)d_in[w0 + 12];
    fp Wv = (fp)d_in[w0 + 13], bv = (fp)d_in[w0 + 14], Wel = (fp)d_in[w0 + 15];
    fp Ws = (fp)d_in[w0 + 16], bs = (fp)d_in[w0 + 17];
    fp g1W = (fp)d_in[w0 + 18], g1b = (fp)d_in[w0 + 19], g2W = (fp)d_in[w0 + 20], g2b = (fp)d_in[w0 + 21];
    fp m0W = (fp)d_in[w0 + 22], m0b = (fp)d_in[w0 + 23], m1W = (fp)d_in[w0 + 24], m1b = (fp)d_in[w0 + 25];
    fp m2W = (fp)d_in[w0 + 26], m2b = (fp)d_in[w0 + 27], m3W = (fp)d_in[w0 + 28], m3b = (fp)d_in[w0 + 29];

    const int* srcArr = ei;
    const int* dstArr = ei + N_EDGES;

    char* wsp = (char*)d_ws;
    auto alloc = [&](size_t bytes) -> void* {
        void* p = (void*)wsp;
        wsp += (bytes + 255) & ~(size_t)255;
        return p;
    };
    u16* qb = (u16*)alloc((size_t)N_NODES * 64 * 2);         // bf16, prescaled 1/8
    u32* kvp = (u32*)alloc((size_t)N_NODES * 64 * 4);        // packed bf16 k|v<<16 per feature
    u16* skbb = (u16*)alloc((size_t)N_NODES * 64 * 2);       // bf16 skip
    u16* hb = (u16*)alloc((size_t)N_NODES * 64 * 2);         // h bf16 (gemm A for layers 1-3)
    u16* xb = (u16*)alloc((size_t)N_NODES * IN_CH * 2);      // x bf16
    u16* hmaxb = (u16*)alloc((size_t)N_NODES * 64 * 2);      // JK max, bf16
    float* gate = (float*)alloc((size_t)N_NODES * 4);
    float* pooled = (float*)alloc(64 * 64 * 4);
    u32* gmaxEnc = (u32*)alloc(N_GRAPHS * 4);
    float* gsum = (float*)alloc(N_GRAPHS * 4);
    int* row_ptr = (int*)alloc((N_NODES + 1) * 4);
    int* cursor = (int*)alloc((size_t)N_NODES * 4);
    int* csr_src = (int*)alloc((size_t)N_EDGES * 4);
    uint4* eab = (uint4*)alloc((size_t)N_EDGES * 16);
    u16* Bp0 = (u16*)alloc((size_t)(IN_CH / 32) * 16 * 512 * 2);
    u16* Bp1 = (u16*)alloc((size_t)(DIM / 32) * 16 * 512 * 2);
    u16* Bp2 = (u16*)alloc((size_t)(DIM / 32) * 16 * 512 * 2);
    u16* Bp3 = (u16*)alloc((size_t)(DIM / 32) * 16 * 512 * 2);
    int* blksum = (int*)alloc(256 * 4);
    (void)ws_size;
    (void)n_in;

    float* outF = (float*)d_out;  // [0..383] preds, [384] total_loss

    // ---- CSR build (by dst) + weight/x conversion ----
    hipMemsetAsync(cursor, 0, (size_t)N_NODES * 4, stream);
    hipMemsetAsync(gmaxEnc, 0, N_GRAPHS * 4, stream);
    hipMemsetAsync(gsum, 0, N_GRAPHS * 4, stream);
    hipMemsetAsync(pooled, 0, 64 * 64 * 4, stream);
    count_kernel<<<(N_EDGES + 255) / 256, 256, 0, stream>>>(dstArr, cursor);
    scan1_kernel<<<NBLK, 512, 0, stream>>>(cursor, row_ptr, blksum);
    scan2_kernel<<<1, 256, 0, stream>>>(blksum);
    scan3_kernel<<<NBLK, 512, 0, stream>>>(row_ptr, blksum, cursor);
    for (int p = 0; p < NPASS; ++p)
        scatter_pass_kernel<<<(N_EDGES + 255) / 256, 256, 0, stream>>>(
            srcArr, dstArr, eattr, cursor, csr_src, eab, p * PASS_SZ, (p + 1) * PASS_SZ);
    cvt_bf16_kernel<<<(N_NODES * IN_CH / 4 + 255) / 256, 256, 0, stream>>>(x, xb, N_NODES * IN_CH / 4);
    packW_kernel<<<((IN_CH / 32) * 16 * 512 + 255) / 256, 256, 0, stream>>>(Wq0, Wk0, Wv0, Ws0, Bp0, IN_CH);
    u16* Bps[3] = {Bp1, Bp2, Bp3};
    for (int i = 0; i < N_CONVS; ++i)
        packW_kernel<<<((DIM / 32) * 16 * 512 + 255) / 256, 256, 0, stream>>>(
            Wq + i * 4096, Wk + i * 4096, Wv + i * 4096, Ws + i * 4096, Bps[i], DIM);

    int nodeGrid = N_NODES / 16;  // 4 nodes per wave, 4 waves per block
    // layer 0 (conv_first, 128 -> 64), ELU, init hmax
    gemm_mfma_kernel<IN_CH><<<N_NODES / 32, 256, 0, stream>>>(xb, Bp0, bq0, bk0, bv0, bs0, qb, kvp, skbb);
    node_kernel<<<nodeGrid, 256, 0, stream>>>(qb, kvp, skbb, eab, We0, row_ptr, csr_src, hb, hmaxb, 1, 1);
    // layers 1..3 (64 -> 64); ELU except last; JK running max
    for (int i = 0; i < N_CONVS; ++i) {
        gemm_mfma_kernel<DIM><<<N_NODES / 32, 256, 0, stream>>>(hb, Bps[i], bq + i * 64, bk + i * 64,
                                                                bv + i * 64, bs + i * 64, qb, kvp, skbb);
        node_kernel<<<nodeGrid, 256, 0, stream>>>(qb, kvp, skbb, eab, Wel + i * 448, row_ptr,
                                                  csr_src, hb, hmaxb, (i < N_CONVS - 1) ? 1 : 0, 0);
    }
    // pooling head: gate -> segmented max -> fused exp/sum/accum -> MLP (divides by gsum)
    gate_kernel<<<N_NODES / 4, 256, 0, stream>>>(hmaxb, g1W, g1b, g2W, g2b, gate);
    gmax_kernel<<<(N_NODES + 255) / 256, 256, 0, stream>>>(gate, batch, gmaxEnc);
    pool_accum_kernel<<<(N_NODES + PCHUNK - 1) / PCHUNK, 256, 0, stream>>>(hmaxb, gate, batch, gmaxEnc,
                                                                           pooled, gsum);
    mlp_kernel<<<6, 256, 0, stream>>>(pooled, gsum, m0W, m0b, m1W, m1b, m2W, m2b, m3W, m3b, outF);
    loss_kernel<<<1, 64, 0, stream>>>(outF, y, outF);
}

// Round 22
// 725.805 us; speedup vs baseline: 1.2050x; 1.0392x over previous
//
#include <hip/hip_runtime.h>
#include <math.h>

#define N_NODES 100000
#define N_EDGES 1600000
#define N_GRAPHS 64
#define IN_CH 128
#define DIM 64
#define N_CONVS 3
#define NBLK 196      // ceil(100000/512)
#define NPASS 4
#define PASS_SZ 25000  // N_NODES / NPASS

typedef const float* fp;
typedef unsigned int u32;
typedef unsigned short u16;
typedef __attribute__((ext_vector_type(8))) short short8v;
typedef __attribute__((ext_vector_type(4))) float f32x4;

__device__ inline u16 rne_bf16(float f) {
    u32 u = __float_as_uint(f);
    return (u16)((u + 0x7fffu + ((u >> 16) & 1u)) >> 16);
}
__device__ inline float bf16_f(u16 w) { return __uint_as_float((u32)w << 16); }
__device__ inline float bf16lo_f(u32 w) { return __uint_as_float(w << 16); }
__device__ inline float bf16hi_f(u32 w) { return __uint_as_float(w & 0xffff0000u); }
// order-preserving float <-> uint encoding (for atomicMax on floats incl. negatives)
__device__ inline u32 f_enc(float f) {
    u32 u = __float_as_uint(f);
    return (u & 0x80000000u) ? ~u : (u | 0x80000000u);
}
__device__ inline float f_dec(u32 e) {
    u32 u = (e & 0x80000000u) ? (e & 0x7fffffffu) : ~e;
    return __uint_as_float(u);
}

// ---------------- CSR build ----------------
__global__ __launch_bounds__(256) void count_kernel(const int* __restrict__ dst, int* __restrict__ cnt) {
    int j = blockIdx.x * 256 + threadIdx.x;
    if (j < N_EDGES) {
        int d = dst[j];
        if ((unsigned)d < N_NODES) atomicAdd(&cnt[d], 1);
    }
}

__global__ __launch_bounds__(512) void scan1_kernel(const int* __restrict__ cnt, int* __restrict__ rp,
                                                    int* __restrict__ blksum) {
    __shared__ int tmp[512];
    int t = threadIdx.x, i = blockIdx.x * 512 + t;
    int v0 = (i < N_NODES) ? cnt[i] : 0;
    tmp[t] = v0;
    __syncthreads();
    for (int off = 1; off < 512; off <<= 1) {
        int add = (t >= off) ? tmp[t - off] : 0;
        __syncthreads();
        tmp[t] += add;
        __syncthreads();
    }
    if (i < N_NODES) rp[i] = tmp[t] - v0;
    if (t == 511) blksum[blockIdx.x] = tmp[511];
}

__global__ __launch_bounds__(256) void scan2_kernel(int* __restrict__ blksum) {
    __shared__ int tmp[256];
    int t = threadIdx.x;
    int v0 = (t < NBLK) ? blksum[t] : 0;
    tmp[t] = v0;
    __syncthreads();
    for (int off = 1; off < 256; off <<= 1) {
        int add = (t >= off) ? tmp[t - off] : 0;
        __syncthreads();
        tmp[t] += add;
        __syncthreads();
    }
    if (t < NBLK) blksum[t] = tmp[t] - v0;
}

__global__ __launch_bounds__(512) void scan3_kernel(int* __restrict__ rp, const int* __restrict__ blksum,
                                                    int* __restrict__ cursor) {
    int t = threadIdx.x, i = blockIdx.x * 512 + t;
    if (i < N_NODES) {
        int v = rp[i] + blksum[blockIdx.x];
        rp[i] = v;
        cursor[i] = v;
    }
    if (i == 0) rp[N_NODES] = N_EDGES;
}

// range-split scatter with inline ea->bf16 pack: only edges with dst in [lo, hi)
__global__ __launch_bounds__(256) void scatter_pass_kernel(const int* __restrict__ src,
                                                           const int* __restrict__ dst, fp ea,
                                                           int* __restrict__ cursor,
                                                           int* __restrict__ csr_src,
                                                           uint4* __restrict__ eab, int lo, int hi) {
    int j = blockIdx.x * 256 + threadIdx.x;
    if (j < N_EDGES) {
        int d = dst[j];
        if (d < lo || d >= hi || (unsigned)d >= N_NODES) return;
        int pos = atomicAdd(&cursor[d], 1);
        if ((unsigned)pos < N_EDGES) {
            int s = src[j];
            csr_src[pos] = ((unsigned)s < N_NODES) ? s : 0;
            size_t sb = (size_t)j * 7;
            u16 b[8];
#pragma unroll
            for (int c = 0; c < 7; ++c) b[c] = rne_bf16(ea[sb + c]);
            b[7] = 0;
            uint4 o;
            o.x = b[0] | ((u32)b[1] << 16);
            o.y = b[2] | ((u32)b[3] << 16);
            o.z = b[4] | ((u32)b[5] << 16);
            o.w = b[6] | ((u32)b[7] << 16);
            eab[pos] = o;
        }
    }
}

// ---------------- x -> bf16 ----------------
__global__ __launch_bounds__(256) void cvt_bf16_kernel(const float* __restrict__ in, u16* __restrict__ out,
                                                       int n4) {
    int i = blockIdx.x * 256 + threadIdx.x;
    if (i < n4) {
        float4 v = reinterpret_cast<const float4*>(in)[i];
        ushort4 o;
        o.x = rne_bf16(v.x); o.y = rne_bf16(v.y); o.z = rne_bf16(v.z); o.w = rne_bf16(v.w);
        reinterpret_cast<ushort4*>(out)[i] = o;
    }
}

// ---------------- pack W (q|k|v|s -> K x 256) into MFMA B-fragment order ----------------
__global__ __launch_bounds__(256) void packW_kernel(fp Wq, fp Wk, fp Wv, fp Ws, u16* __restrict__ Bp,
                                                    int K) {
    int total = (K / 32) * 16 * 512;
    int tid = blockIdx.x * 256 + threadIdx.x;
    if (tid >= total) return;
    int j = tid & 7, l = (tid >> 3) & 63, fragid = tid >> 9;
    int tk = fragid >> 4, gtn = fragid & 15;
    int k = tk * 32 + ((l >> 4) << 3) + j;
    int n = (gtn << 4) + (l & 15);
    int mat = n >> 6, cn = n & 63;
    fp W = mat == 0 ? Wq : mat == 1 ? Wk : mat == 2 ? Wv : Ws;
    Bp[tid] = rne_bf16(W[k * 64 + cn]);
}

// ---------------- fused MFMA GEMM: q(bf16, *1/8) | kv(dense u32 via LDS pack) | skip(bf16) ----------------
template <int K>
__global__ __launch_bounds__(256) void gemm_mfma_kernel(
    const u16* __restrict__ A, const u16* __restrict__ Bp,
    fp bq, fp bk, fp bv, fp bs,
    u16* __restrict__ qb, u32* __restrict__ kvp, u16* __restrict__ skbb) {
    constexpr int NTK = K / 32;
    __shared__ u16 kls[32][64];
    int wave = threadIdx.x >> 6;  // 0:q 1:k 2:v 3:skip
    int l = threadIdx.x & 63;
    int lr = l & 15, lg = l >> 4;
    int row0 = blockIdx.x * 32;
    short8v a[2][NTK];
#pragma unroll
    for (int mi = 0; mi < 2; ++mi)
#pragma unroll
        for (int tk = 0; tk < NTK; ++tk)
            a[mi][tk] = *reinterpret_cast<const short8v*>(
                &A[(size_t)(row0 + mi * 16 + lr) * K + tk * 32 + lg * 8]);
    f32x4 c[2][4] = {};
#pragma unroll
    for (int tn = 0; tn < 4; ++tn) {
        int gtn = wave * 4 + tn;
#pragma unroll
        for (int tk = 0; tk < NTK; ++tk) {
            short8v b = *reinterpret_cast<const short8v*>(&Bp[((size_t)(tk * 16 + gtn) * 64 + l) * 8]);
            c[0][tn] = __builtin_amdgcn_mfma_f32_16x16x32_bf16(a[0][tk], b, c[0][tn], 0, 0, 0);
            c[1][tn] = __builtin_amdgcn_mfma_f32_16x16x32_bf16(a[1][tk], b, c[1][tn], 0, 0, 0);
        }
    }
    fp bias = wave == 0 ? bq : wave == 1 ? bk : wave == 2 ? bv : bs;
    if (wave == 1) {  // stage k into LDS
#pragma unroll
        for (int tn = 0; tn < 4; ++tn) {
            int cl = tn * 16 + lr;
            float bb = bias[cl];
#pragma unroll
            for (int mi = 0; mi < 2; ++mi)
#pragma unroll
                for (int r = 0; r < 4; ++r) {
                    int rr = mi * 16 + lg * 4 + r;
                    kls[rr][cl] = rne_bf16(c[mi][tn][r] + bb);
                }
        }
    }
    __syncthreads();
    if (wave == 1) return;
#pragma unroll
    for (int tn = 0; tn < 4; ++tn) {
        int cl = tn * 16 + lr;
        float bb = bias[cl];
#pragma unroll
        for (int mi = 0; mi < 2; ++mi)
#pragma unroll
            for (int r = 0; r < 4; ++r) {
                int rr = mi * 16 + lg * 4 + r;
                size_t row = row0 + rr;
                float val = c[mi][tn][r] + bb;
                if (wave == 0) qb[row * 64 + cl] = rne_bf16(val * 0.125f);
                else if (wave == 3) skbb[row * 64 + cl] = rne_bf16(val);
                else kvp[row * 64 + cl] = (u32)kls[rr][cl] | ((u32)rne_bf16(val) << 16);
            }
    }
}

// ---------------- per-node edge aggregation: 4 nodes/wave, 16 lanes/node, e-channel-per-lane ----------------
__global__ __launch_bounds__(256) void node_kernel(
    const u16* __restrict__ qb, const u32* __restrict__ kvp,
    const u16* __restrict__ skbb, const uint4* __restrict__ eab, fp We,
    const int* __restrict__ row_ptr, const int* __restrict__ csr_src,
    u16* __restrict__ hb, u16* __restrict__ hmaxb, int act, int initmax) {
    int tid = threadIdx.x;
    int lane = tid & 63;
    int g = lane >> 4, fl = lane & 15;
    int gbase = g << 4;
    int n = blockIdx.x * 16 + (tid >> 6) * 4 + g;
    int f0 = fl * 4;
    ushort4 qv = *reinterpret_cast<const ushort4*>(&qb[(size_t)n * 64 + f0]);
    float4 q4;
    q4.x = bf16_f(qv.x); q4.y = bf16_f(qv.y); q4.z = bf16_f(qv.z); q4.w = bf16_f(qv.w);
    // qw_own: lane fl (fl<7) keeps qw[fl] = sum_f q[f]*We[fl][f]; other lanes 0
    float qw_own = 0.f;
#pragma unroll
    for (int c = 0; c < 7; ++c) {
        float4 w4 = *reinterpret_cast<const float4*>(&We[c * 64 + f0]);
        float t = q4.x * w4.x + q4.y * w4.y + q4.z * w4.z + q4.w * w4.w;
        t += __shfl_xor(t, 1);
        t += __shfl_xor(t, 2);
        t += __shfl_xor(t, 4);
        t += __shfl_xor(t, 8);
        if (fl == c) qw_own = t;
    }
    int beg = row_ptr[n], end = row_ptr[n + 1];
    float s = 0.f;
    float ax = 0.f, ay = 0.f, az = 0.f, aw = 0.f;
    float r_own = 0.f;  // sum pe * ea[fl]  (lane's channel)

    for (int p = beg; p < end; p += 4) {
        int svi = p + (fl & 3);
        svi = svi < end ? svi : end - 1;
        int sv = csr_src[svi];
#pragma unroll
        for (int j = 0; j < 4; ++j) {
            int pj = p + j;
            int pc = pj < end ? pj : end - 1;
            int sn = __shfl(sv, gbase + j);
            uint4 kv4 = *reinterpret_cast<const uint4*>(&kvp[(size_t)sn * 64 + f0]);
            uint4 e4 = eab[pc];
            // lane's edge-attr channel (fl<7 valid; fl==7 -> packed 0; fl>=8 garbage but unused)
            u32 w01 = (fl & 2) ? e4.y : e4.x;
            u32 w23 = (fl & 2) ? e4.w : e4.z;
            u32 wsel = (fl & 4) ? w23 : w01;
            float e_own = (fl & 1) ? bf16hi_f(wsel) : bf16lo_f(wsel);
            float kf0 = bf16lo_f(kv4.x), vf0 = bf16hi_f(kv4.x);
            float kf1 = bf16lo_f(kv4.y), vf1 = bf16hi_f(kv4.y);
            float kf2 = bf16lo_f(kv4.z), vf2 = bf16hi_f(kv4.z);
            float kf3 = bf16lo_f(kv4.w), vf3 = bf16hi_f(kv4.w);
            // fused alpha: butterfly over (q.k partials + qw[fl]*ea[fl])
            float d = q4.x * kf0 + q4.y * kf1 + q4.z * kf2 + q4.w * kf3 + qw_own * e_own;
            d += __shfl_xor(d, 1);
            d += __shfl_xor(d, 2);
            d += __shfl_xor(d, 4);
            d += __shfl_xor(d, 8);
            float pe = (pj < end) ? __expf(d) : 0.f;
            s += pe;
            ax += pe * vf0; ay += pe * vf1; az += pe * vf2; aw += pe * vf3;
            r_own += pe * e_own;
        }
    }
    float inv = 1.f / (s + 1e-16f);
    float o0 = ax, o1 = ay, o2 = az, o3 = aw;
#pragma unroll
    for (int c = 0; c < 7; ++c) {
        float rc = __shfl(r_own, gbase + c);
        o0 += We[c * 64 + f0 + 0] * rc;
        o1 += We[c * 64 + f0 + 1] * rc;
        o2 += We[c * 64 + f0 + 2] * rc;
        o3 += We[c * 64 + f0 + 3] * rc;
    }
    ushort4 skv = *reinterpret_cast<const ushort4*>(&skbb[(size_t)n * 64 + f0]);
    float4 res;
    res.x = o0 * inv + bf16_f(skv.x);
    res.y = o1 * inv + bf16_f(skv.y);
    res.z = o2 * inv + bf16_f(skv.z);
    res.w = o3 * inv + bf16_f(skv.w);
    if (act) {
        res.x = res.x > 0.f ? res.x : (__expf(res.x) - 1.f);
        res.y = res.y > 0.f ? res.y : (__expf(res.y) - 1.f);
        res.z = res.z > 0.f ? res.z : (__expf(res.z) - 1.f);
        res.w = res.w > 0.f ? res.w : (__expf(res.w) - 1.f);
    }
    ushort4 hb4;
    hb4.x = rne_bf16(res.x); hb4.y = rne_bf16(res.y); hb4.z = rne_bf16(res.z); hb4.w = rne_bf16(res.w);
    *reinterpret_cast<ushort4*>(&hb[(size_t)n * 64 + f0]) = hb4;
    if (initmax) {
        *reinterpret_cast<ushort4*>(&hmaxb[(size_t)n * 64 + f0]) = hb4;
    } else {
        ushort4 hm4 = *reinterpret_cast<const ushort4*>(&hmaxb[(size_t)n * 64 + f0]);
        hm4.x = rne_bf16(fmaxf(bf16_f(hm4.x), res.x));
        hm4.y = rne_bf16(fmaxf(bf16_f(hm4.y), res.y));
        hm4.z = rne_bf16(fmaxf(bf16_f(hm4.z), res.z));
        hm4.w = rne_bf16(fmaxf(bf16_f(hm4.w), res.w));
        *reinterpret_cast<ushort4*>(&hmaxb[(size_t)n * 64 + f0]) = hm4;
    }
}

// ---------------- gate MLP per node (bf16 hmax input, no atomics) ----------------
__global__ __launch_bounds__(256) void gate_kernel(const u16* __restrict__ h, fp g1W, fp g1b, fp g2W,
                                                   fp g2b, float* __restrict__ gate) {
    __shared__ float hs[4][64];
    int w = threadIdx.x >> 6, lane = threadIdx.x & 63;
    int n = blockIdx.x * 4 + w;
    hs[w][lane] = bf16_f(h[(size_t)n * 64 + lane]);
    __syncthreads();
    float a = 0.f;
    for (int f = 0; f < 64; ++f) a += hs[w][f] * g1W[f * 64 + lane];
    a = fmaxf(a + g1b[lane], 0.f);
    float val = a * g2W[lane];
#pragma unroll
    for (int off = 32; off; off >>= 1) val += __shfl_xor(val, off);
    if (lane == 0) gate[n] = val + g2b[0];
}

// per-graph max via wave-segmented atomicMax (~1600 atomics total)
__global__ __launch_bounds__(256) void gmax_kernel(const float* __restrict__ gate,
                                                   const int* __restrict__ batch,
                                                   u32* __restrict__ gmaxEnc) {
    int i = blockIdx.x * 256 + threadIdx.x;
    if (i >= N_NODES) return;
    int lane = threadIdx.x & 63;
    int g = batch[i];
    u32 e = f_enc(gate[i]);
    int waveBase = i - lane;
    if (waveBase + 63 < N_NODES) {
        int g0 = __shfl(g, 0), g63 = __shfl(g, 63);
        if (g0 == g63) {
            u32 t = e;
#pragma unroll
            for (int off = 32; off; off >>= 1) t = max(t, (u32)__shfl_xor((int)t, off));
            if (lane == 0) atomicMax(&gmaxEnc[g], t);
            return;
        }
    }
    atomicMax(&gmaxEnc[g], e);
}

// fused exp + per-graph sum + weighted accumulation (bf16 h)
#define PCHUNK 256
__global__ __launch_bounds__(256) void pool_accum_kernel(const u16* __restrict__ h,
                                                         const float* __restrict__ gate,
                                                         const int* __restrict__ batch,
                                                         const u32* __restrict__ gmaxEnc,
                                                         float* __restrict__ pooled,
                                                         float* __restrict__ gsum) {
    int w = threadIdx.x >> 6, lane = threadIdx.x & 63;
    int base = blockIdx.x * PCHUNK;
    float acc = 0.f, gacc = 0.f;
    int cur = -1;
    for (int t = 0; t < PCHUNK / 4; ++t) {
        int i = base + w + 4 * t;
        if (i >= N_NODES) break;
        int g = batch[i];
        if (g != cur) {
            if (cur >= 0) {
                atomicAdd(&pooled[cur * 64 + lane], acc);
                if (lane == 0) atomicAdd(&gsum[cur], gacc);
            }
            acc = 0.f;
            gacc = 0.f;
            cur = g;
        }
        float p = __expf(gate[i] - f_dec(gmaxEnc[g]));
        gacc += p;
        acc += p * bf16_f(h[(size_t)i * 64 + lane]);
    }
    if (cur >= 0) {
        atomicAdd(&pooled[cur * 64 + lane], acc);
        if (lane == 0) atomicAdd(&gsum[cur], gacc);
    }
}

// ---------------- 6-expert MLP head (f32 output); divides pooled by gsum ----------------
__global__ __launch_bounds__(256) void mlp_kernel(const float* __restrict__ pooled,
                                                  const float* __restrict__ gsum, fp m0W, fp m0b, fp m1W,
                                                  fp m1b, fp m2W, fp m2b, fp m3W, fp m3b,
                                                  float* __restrict__ out) {
    int e = blockIdx.x, tid = threadIdx.x;
    __shared__ float P[64 * 64];
    __shared__ float A1[64 * 32];
    __shared__ float A2[64 * 16];
    __shared__ float A3[64 * 8];
    for (int i = tid; i < 64 * 64; i += 256) P[i] = pooled[i] / (gsum[i >> 6] + 1e-16f);
    __syncthreads();
    fp W0 = m0W + e * 64 * 32; fp B0 = m0b + e * 32;
    for (int i = tid; i < 64 * 32; i += 256) {
        int g = i >> 5, c = i & 31;
        float a = B0[c];
        for (int f = 0; f < 64; ++f) a += P[g * 64 + f] * W0[f * 32 + c];
        A1[i] = a > 0.f ? a : (__expf(a) - 1.f);
    }
    __syncthreads();
    fp W1 = m1W + e * 32 * 16; fp B1 = m1b + e * 16;
    for (int i = tid; i < 64 * 16; i += 256) {
        int g = i >> 4, c = i & 15;
        float a = B1[c];
        for (int f = 0; f < 32; ++f) a += A1[g * 32 + f] * W1[f * 16 + c];
        A2[i] = a > 0.f ? a : (__expf(a) - 1.f);
    }
    __syncthreads();
    fp W2 = m2W + e * 16 * 8; fp B2 = m2b + e * 8;
    for (int i = tid; i < 64 * 8; i += 256) {
        int g = i >> 3, c = i & 7;
        float a = B2[c];
        for (int f = 0; f < 16; ++f) a += A2[g * 16 + f] * W2[f * 8 + c];
        A3[i] = a > 0.f ? a : (__expf(a) - 1.f);
    }
    __syncthreads();
    fp W3 = m3W + e * 8;
    if (tid < 64) {
        int g = tid;
        float a = m3b[e];
        for (int j = 0; j < 8; ++j) a += A3[g * 8 + j] * W3[j];
        out[g * 6 + e] = a;
    }
}

__global__ __launch_bounds__(64) void loss_kernel(const float* __restrict__ preds, fp y,
                                                  float* __restrict__ out) {
    int lane = threadIdx.x;
    float lsum = 0.f;
    if (lane < 6) {
        float acc = 0.f;
        for (int g = 0; g < 64; ++g) {
            float d = preds[g * 6 + lane] - y[g * 6 + lane];
            acc += d * d;
        }
        lsum = sqrtf(acc / 64.f);
    }
#pragma unroll
    for (int off = 32; off; off >>= 1) lsum += __shfl_xor(lsum, off);
    if (lane == 0) out[384] = lsum;
}

extern "C" void kernel_launch(void* const* d_in, const int* in_sizes, int n_in, void* d_out, int out_size,
                              void* d_ws, size_t ws_size, hipStream_t stream) {
    bool dictOrder = (in_sizes[1] == 2 * N_EDGES);
    int iEI = dictOrder ? 1 : 33;
    int iEA = dictOrder ? 2 : 1;
    int iBT = dictOrder ? 3 : 34;
    int iY  = dictOrder ? 4 : 2;
    int w0  = dictOrder ? 5 : 3;

    fp x = (fp)d_in[0];
    const int* ei = (const int*)d_in[iEI];
    fp eattr = (fp)d_in[iEA];
    const int* batch = (const int*)d_in[iBT];
    fp y = (fp)d_in[iY];
    fp Wq0 = (fp)d_in[w0 + 0], bq0 = (fp)d_in[w0 + 1], Wk0 = (fp)d_in[w0 + 2], bk0 = (fp)d_in[w0 + 3];
    fp Wv0 = (fp)d_in[w0 + 4], bv0 = (fp)d_in[w0 + 5], We0 = (fp)d_in[w0 + 6];
    fp Ws0 = (fp)d_in[w0 + 7], bs0 = (fp)d_in[w0 + 8];
    fp Wq = (fp)d_in[w0 + 9], bq = (fp)d_in[w0 + 10], Wk = (fp)d_in[w0 + 11], bk = (fp)d_in[w0 + 12];
    fp Wv = (fp)d_in[w0 + 13], bv = (fp)d_in[w0 + 14], Wel = (fp)d_in[w0 + 15];
    fp Ws = (fp)d_in[w0 + 16], bs = (fp)d_in[w0 + 17];
    fp g1W = (fp)d_in[w0 + 18], g1b = (fp)d_in[w0 + 19], g2W = (fp)d_in[w0 + 20], g2b = (fp)d_in[w0 + 21];
    fp m0W = (fp)d_in[w0 + 22], m0b = (fp)d_in[w0 + 23], m1W = (fp)d_in[w0 + 24], m1b = (fp)d_in[w0 + 25];
    fp m2W = (fp)d_in[w0 + 26], m2b = (fp)d_in[w0 + 27], m3W = (fp)d_in[w0 + 28], m3b = (fp)d_in[w0 + 29];

    const int* srcArr = ei;
    const int* dstArr = ei + N_EDGES;

    char* wsp = (char*)d_ws;
    auto alloc = [&](size_t bytes) -> void* {
        void* p = (void*)wsp;
        wsp += (bytes + 255) & ~(size_t)255;
        return p;
    };
    u16* qb = (u16*)alloc((size_t)N_NODES * 64 * 2);         // bf16, prescaled 1/8
    u32* kvp = (u32*)alloc((size_t)N_NODES * 64 * 4);        // packed bf16 k|v<<16 per feature
    u16* skbb = (u16*)alloc((size_t)N_NODES * 64 * 2);       // bf16 skip
    u16* hb = (u16*)alloc((size_t)N_NODES * 64 * 2);         // h bf16 (gemm A for layers 1-3)
    u16* xb = (u16*)alloc((size_t)N_NODES * IN_CH * 2);      // x bf16
    u16* hmaxb = (u16*)alloc((size_t)N_NODES * 64 * 2);      // JK max, bf16
    float* gate = (float*)alloc((size_t)N_NODES * 4);
    float* pooled = (float*)alloc(64 * 64 * 4);
    u32* gmaxEnc = (u32*)alloc(N_GRAPHS * 4);
    float* gsum = (float*)alloc(N_GRAPHS * 4);
    int* row_ptr = (int*)alloc((N_NODES + 1) * 4);
    int* cursor = (int*)alloc((size_t)N_NODES * 4);
    int* csr_src = (int*)alloc((size_t)N_EDGES * 4);
    uint4* eab = (uint4*)alloc((size_t)N_EDGES * 16);
    u16* Bp0 = (u16*)alloc((size_t)(IN_CH / 32) * 16 * 512 * 2);
    u16* Bp1 = (u16*)alloc((size_t)(DIM / 32) * 16 * 512 * 2);
    u16* Bp2 = (u16*)alloc((size_t)(DIM / 32) * 16 * 512 * 2);
    u16* Bp3 = (u16*)alloc((size_t)(DIM / 32) * 16 * 512 * 2);
    int* blksum = (int*)alloc(256 * 4);
    (void)ws_size;
    (void)n_in;

    float* outF = (float*)d_out;  // [0..383] preds, [384] total_loss

    // ---- CSR build (by dst) + weight/x conversion ----
    hipMemsetAsync(cursor, 0, (size_t)N_NODES * 4, stream);
    hipMemsetAsync(gmaxEnc, 0, N_GRAPHS * 4, stream);
    hipMemsetAsync(gsum, 0, N_GRAPHS * 4, stream);
    hipMemsetAsync(pooled, 0, 64 * 64 * 4, stream);
    count_kernel<<<(N_EDGES + 255) / 256, 256, 0, stream>>>(dstArr, cursor);
    scan1_kernel<<<NBLK, 512, 0, stream>>>(cursor, row_ptr, blksum);
    scan2_kernel<<<1, 256, 0, stream>>>(blksum);
    scan3_kernel<<<NBLK, 512, 0, stream>>>(row_ptr, blksum, cursor);
    for (int p = 0; p < NPASS; ++p)
        scatter_pass_kernel<<<(N_EDGES + 255) / 256, 256, 0, stream>>>(
            srcArr, dstArr, eattr, cursor, csr_src, eab, p * PASS_SZ, (p + 1) * PASS_SZ);
    cvt_bf16_kernel<<<(N_NODES * IN_CH / 4 + 255) / 256, 256, 0, stream>>>(x, xb, N_NODES * IN_CH / 4);
    packW_kernel<<<((IN_CH / 32) * 16 * 512 + 255) / 256, 256, 0, stream>>>(Wq0, Wk0, Wv0, Ws0, Bp0, IN_CH);
    u16* Bps[3] = {Bp1, Bp2, Bp3};
    for (int i = 0; i < N_CONVS; ++i)
        packW_kernel<<<((DIM / 32) * 16 * 512 + 255) / 256, 256, 0, stream>>>(
            Wq + i * 4096, Wk + i * 4096, Wv + i * 4096, Ws + i * 4096, Bps[i], DIM);

    int nodeGrid = N_NODES / 16;  // 4 nodes per wave, 4 waves per block
    // layer 0 (conv_first, 128 -> 64), ELU, init hmax
    gemm_mfma_kernel<IN_CH><<<N_NODES / 32, 256, 0, stream>>>(xb, Bp0, bq0, bk0, bv0, bs0, qb, kvp, skbb);
    node_kernel<<<nodeGrid, 256, 0, stream>>>(qb, kvp, skbb, eab, We0, row_ptr, csr_src, hb, hmaxb, 1, 1);
    // layers 1..3 (64 -> 64); ELU except last; JK running max
    for (int i = 0; i < N_CONVS; ++i) {
        gemm_mfma_kernel<DIM><<<N_NODES / 32, 256, 0, stream>>>(hb, Bps[i], bq + i * 64, bk + i * 64,
                                                                bv + i * 64, bs + i * 64, qb, kvp, skbb);
        node_kernel<<<nodeGrid, 256, 0, stream>>>(qb, kvp, skbb, eab, Wel + i * 448, row_ptr,
                                                  csr_src, hb, hmaxb, (i < N_CONVS - 1) ? 1 : 0, 0);
    }
    // pooling head: gate -> segmented max -> fused exp/sum/accum -> MLP (divides by gsum)
    gate_kernel<<<N_NODES / 4, 256, 0, stream>>>(hmaxb, g1W, g1b, g2W, g2b, gate);
    gmax_kernel<<<(N_NODES + 255) / 256, 256, 0, stream>>>(gate, batch, gmaxEnc);
    pool_accum_kernel<<<(N_NODES + PCHUNK - 1) / PCHUNK, 256, 0, stream>>>(hmaxb, gate, batch, gmaxEnc,
                                                                           pooled, gsum);
    mlp_kernel<<<6, 256, 0, stream>>>(pooled, gsum, m0W, m0b, m1W, m1b, m2W, m2b, m3W, m3b, outF);
    loss_kernel<<<1, 64, 0, stream>>>(outF, y, outF);
}